// Round 7
// baseline (1736.919 us; speedup 1.0000x reference)
//
#include <hip/hip_runtime.h>
#include <math.h>

#define N_NODES 2048
#define NE      16384
#define NB      64
#define FIN     92
#define DD      128
#define HH_     4
#define CC_     128
#define HC_     512
#define C3_     384
#define NL      5
#define EPSV    1e-5f

// per-layer packed fp16 weight block offsets (halves)
#define LWH        540672
#define OFF_QKVST  0        // [1664][128]
#define OFF_W12T   212992   // [768][128]
#define OFF_WM3T   311296   // [384][128]
#define OFF_WMSGT  360448   // [128][384]
#define OFF_WET    409600   // [512][128]
#define OFF_WCATT  475136   // [128][512]
#define EX0        (5*LWH)
#define OFF_EMBT   (EX0)            // [128][96]
#define OFF_W1T    (EX0+12288)      // [128][128]
#define OFF_W2T    (EX0+28672)      // [128][128]
#define OFF_FCT    (EX0+45056)      // [128][128]
#define TOT_H      (EX0+61440)
#define TOT_ALL    (TOT_H + 5*1664)

struct alignas(16) F4 { float v[4]; };
typedef _Float16 f16x4 __attribute__((ext_vector_type(4)));
typedef _Float16 f16x8 __attribute__((ext_vector_type(8)));
typedef float f32x4 __attribute__((ext_vector_type(4)));
union H4 { f16x4 h; uint2 u; };
union H8 { f16x8 h; uint4 u; };

// ---------------- weight prep: transpose + fp16 convert, all layers ----------------
__global__ void wprep_kernel(const float* __restrict__ wq, const float* __restrict__ bq,
                             const float* __restrict__ wk, const float* __restrict__ bk,
                             const float* __restrict__ wv, const float* __restrict__ bv,
                             const float* __restrict__ wskip, const float* __restrict__ bskip,
                             const float* __restrict__ wm, const float* __restrict__ wmsg,
                             const float* __restrict__ we, const float* __restrict__ wcat,
                             const float* __restrict__ emb_w, const float* __restrict__ rbf_w1,
                             const float* __restrict__ rbf_w2, const float* __restrict__ fc_w,
                             _Float16* __restrict__ wb, float* __restrict__ bb)
{
    int idx = blockIdx.x * 256 + threadIdx.x;
    if (idx < 5 * LWH) {
        int l = idx / LWH, r = idx % LWH;
        float val;
        if (r < 212992) {
            int n = r >> 7, kk = r & 127;
            if (n < 512)       val = wq[(size_t)l * 65536 + kk * 512 + n];
            else if (n < 1024) val = wk[(size_t)l * 65536 + kk * 512 + (n - 512)];
            else if (n < 1536) val = wv[(size_t)l * 65536 + kk * 512 + (n - 1024)];
            else               val = wskip[(size_t)l * 16384 + kk * 128 + (n - 1536)];
        } else if (r < 311296) {
            int t = r - 212992; int n = t >> 7, kk = t & 127;
            val = (n < 384) ? wm[(size_t)l * 147456 + kk * 384 + n]
                            : wm[(size_t)l * 147456 + (128 + kk) * 384 + (n - 384)];
        } else if (r < 360448) {
            int t = r - 311296; int n = t >> 7, kk = t & 127;
            val = wm[(size_t)l * 147456 + (256 + kk) * 384 + n];
        } else if (r < 409600) {
            int t = r - 360448; int n = t / 384, kk = t % 384;
            val = wmsg[(size_t)l * 49152 + kk * 128 + n];
        } else if (r < 475136) {
            int t = r - 409600; int n = t >> 7, kk = t & 127;
            val = we[(size_t)l * 65536 + kk * 512 + n];
        } else {
            int t = r - 475136; int n = t >> 9, kk = t & 511;
            val = wcat[(size_t)l * 65536 + kk * 128 + n];
        }
        wb[idx] = (_Float16)val;
    } else if (idx < TOT_H) {
        int t = idx - EX0;
        float val;
        if (t < 12288)      { int n = t / 96, kk = t % 96; val = (kk < FIN) ? emb_w[kk * 128 + n] : 0.f; }
        else if (t < 28672) { int t2 = t - 12288; int n = t2 >> 7, kk = t2 & 127; val = rbf_w1[kk * 128 + n]; }
        else if (t < 45056) { int t2 = t - 28672; int n = t2 >> 7, kk = t2 & 127; val = rbf_w2[kk * 128 + n]; }
        else                { int t2 = t - 45056; int n = t2 >> 7, kk = t2 & 127; val = fc_w[kk * 128 + n]; }
        wb[idx] = (_Float16)val;
    } else if (idx < TOT_ALL) {
        int t = idx - TOT_H;
        int l = t / 1664, n = t % 1664;
        float val;
        if (n < 512)       val = bq[l * 512 + n];
        else if (n < 1024) val = bk[l * 512 + n - 512];
        else if (n < 1536) val = bv[l * 512 + n - 1024];
        else               val = bskip[l * 128 + n - 1536];
        bb[t] = val;
    }
}

// ---------------- x -> fp16 padded to 96 ----------------
__global__ void xpack_kernel(const float* __restrict__ x, _Float16* __restrict__ x16)
{
    int idx = blockIdx.x * 256 + threadIdx.x;
    if (idx >= N_NODES * 96) return;
    int n = idx / 96, kk = idx % 96;
    x16[idx] = (kk < FIN) ? (_Float16)x[n * FIN + kk] : (_Float16)0.f;
}

// ---------------- RBF expansion (fp16 out) ----------------
__global__ void rbf_kernel(const float* __restrict__ eattr, _Float16* __restrict__ rbf)
{
    int idx = blockIdx.x * 256 + threadIdx.x;
    int e = idx >> 7, c = idx & 127;
    float x0 = eattr[e * 3 + 0], x1 = eattr[e * 3 + 1], x2 = eattr[e * 3 + 2];
    float d = sqrtf(x0 * x0 + x1 * x1 + x2 * x2);
    float ctr = (8.0f / 127.0f) * (float)c;
    float t = d - ctr;
    rbf[idx] = (_Float16)expf(-15.875f * t * t);
}

// ---------------- unified fp16 MFMA GEMM ----------------
template<int AMODE, int ACT, bool OUT_F32, bool SPLITK>
__global__ __launch_bounds__(256) void gemm16(
    const void* __restrict__ Av, int lda,
    const _Float16* __restrict__ Bt, int ldb, int bkoff,
    const float* __restrict__ bias,
    void* __restrict__ Cv, int ldc, int K)
{
    __shared__ alignas(16) _Float16 As[128 * 40];
    __shared__ alignas(16) _Float16 Bs[128 * 40];
    const int tid = threadIdx.x;
    const int w = tid >> 6, l = tid & 63;
    const int g = l >> 4, c = l & 15;
    const int row0 = blockIdx.x * 128;
    const int col0 = blockIdx.y * 128;
    int k0 = 0, kend = K;
    if (SPLITK) { int ks = K / gridDim.z; k0 = blockIdx.z * ks; kend = k0 + ks; }
    f32x4 acc[2][8] = {};
    for (int kb = k0; kb < kend; kb += 32) {
        __syncthreads();
        #pragma unroll
        for (int i = 0; i < 2; ++i) {
            int p = tid + 256 * i;
            int r = p >> 2, q = p & 3;
            *(uint4*)&Bs[r * 40 + q * 8] =
                *(const uint4*)&Bt[(size_t)(col0 + r) * ldb + bkoff + kb + q * 8];
            if (AMODE == 1) {
                const float* Af = (const float*)Av;
                const float* ap = Af + (size_t)(row0 + r) * lda + kb + q * 8;
                F4 x0 = *(const F4*)ap;
                F4 x1 = *(const F4*)(ap + 4);
                union { _Float16 h[8]; uint4 u; } cv;
                #pragma unroll
                for (int j = 0; j < 4; ++j) { cv.h[j] = (_Float16)x0.v[j]; cv.h[4 + j] = (_Float16)x1.v[j]; }
                *(uint4*)&As[r * 40 + q * 8] = cv.u;
            } else if (AMODE == 2) {
                const _Float16* Ah = (const _Float16*)Av;
                int row = row0 + r;
                *(uint4*)&As[r * 40 + q * 8] =
                    *(const uint4*)&Ah[(size_t)(row >> 2) * lda + (row & 3) * 128 + kb + q * 8];
            } else {
                const _Float16* Ah = (const _Float16*)Av;
                *(uint4*)&As[r * 40 + q * 8] =
                    *(const uint4*)&Ah[(size_t)(row0 + r) * lda + kb + q * 8];
            }
        }
        __syncthreads();
        f16x8 af[2], bf[8];
        #pragma unroll
        for (int mi = 0; mi < 2; ++mi)
            af[mi] = *(const f16x8*)&As[(w * 32 + mi * 16 + c) * 40 + g * 8];
        #pragma unroll
        for (int ni = 0; ni < 8; ++ni)
            bf[ni] = *(const f16x8*)&Bs[(ni * 16 + c) * 40 + g * 8];
        #pragma unroll
        for (int mi = 0; mi < 2; ++mi)
            #pragma unroll
            for (int ni = 0; ni < 8; ++ni)
                acc[mi][ni] = __builtin_amdgcn_mfma_f32_16x16x32_f16(af[mi], bf[ni], acc[mi][ni], 0, 0, 0);
    }
    const bool addb = bias && (!SPLITK || blockIdx.z == 0);
    #pragma unroll
    for (int mi = 0; mi < 2; ++mi)
        #pragma unroll
        for (int ni = 0; ni < 8; ++ni)
            #pragma unroll
            for (int i = 0; i < 4; ++i) {
                int row = row0 + w * 32 + mi * 16 + g * 4 + i;
                int col = col0 + ni * 16 + c;
                float v = acc[mi][ni][i] + (addb ? bias[col] : 0.f);
                if (ACT == 1) v = fmaxf(v, 0.f) + log1pf(expf(-fabsf(v)));
                else if (ACT == 2) v = v / (1.f + expf(-v));
                if (SPLITK)       atomicAdd((float*)Cv + (size_t)row * ldc + col, v);
                else if (OUT_F32) ((float*)Cv)[(size_t)row * ldc + col] = v;
                else              ((_Float16*)Cv)[(size_t)row * ldc + col] = (_Float16)v;
            }
}

// ---------------- fused edge kernel v2: swapped-operand, zero-LDS, zero-barrier ----
// Each lane owns ONE edge-head row (row = blk*64 + w*16 + c); lanes (c, g=0..3)
// of a wave split that row's columns. P3 and GEMM2 use swapped mfma operands so
// results are lane-local; only cross-lane ops are __shfl (within wave).
__global__ __launch_bounds__(256) void fused_edge_kernel(
    const _Float16* __restrict__ qkvs,   // [2048][1664]
    const _Float16* __restrict__ e16,    // [65536][128]
    const _Float16* __restrict__ p12,    // [8192][768]
    const _Float16* __restrict__ wm3T,   // [384][128]
    const _Float16* __restrict__ wmsgT,  // [128][384]
    const float* __restrict__ bm, const float* __restrict__ lag, const float* __restrict__ lab,
    const float* __restrict__ bmsg, const float* __restrict__ lmg, const float* __restrict__ lmb,
    const int* __restrict__ src, const int* __restrict__ dst,
    float* __restrict__ agg)
{
    const int tid = threadIdx.x;
    const int w = tid >> 6, l = tid & 63;
    const int g = l >> 4, c = l & 15;
    const int row_g = blockIdx.x * 64 + w * 16 + c;   // global edge-head row
    const int edge = row_g >> 2, hh = row_g & 3;
    const int nd = dst[edge], ns = src[edge];
    const float ISQ = 0.05103103630798287f;           // 1/sqrt(384)

    const _Float16* qp  = qkvs + (size_t)nd * 1664 + hh * 128;
    const _Float16* kip = qkvs + (size_t)nd * 1664 + 512 + hh * 128;
    const _Float16* kjp = qkvs + (size_t)ns * 1664 + 512 + hh * 128;
    const _Float16* ep  = e16 + (size_t)row_g * 128;

    // e-row MFMA B-fragments (k = ks*32 + g*8 .. +8)
    f16x8 af3[4];
    #pragma unroll
    for (int ks = 0; ks < 4; ++ks)
        af3[ks] = *(const f16x8*)(ep + ks * 32 + g * 8);

    // ---- phase 1: alpha LN stats over this row's 384 cols (this lane: 96) ----
    f16x4 qv[8], kiv[8], kjv[8], ev[8];
    float s1 = 0.f, s2 = 0.f;
    #pragma unroll
    for (int m = 0; m < 4; ++m)
        #pragma unroll
        for (int nt = 0; nt < 2; ++nt) {
            int q8 = m * 2 + nt;
            int cc = m * 32 + nt * 16 + g * 4;
            qv[q8]  = *(const f16x4*)(qp + cc);
            kiv[q8] = *(const f16x4*)(kip + cc);
            kjv[q8] = *(const f16x4*)(kjp + cc);
            ev[q8]  = *(const f16x4*)(ep + cc);
            #pragma unroll
            for (int i = 0; i < 4; ++i) {
                float q = (float)qv[q8][i];
                float a0 = q * (float)kiv[q8][i] * ISQ;
                float a1 = q * (float)kjv[q8][i] * ISQ;
                float a2 = q * (float)ev[q8][i] * ISQ;
                s1 += a0 + a1 + a2;
                s2 += a0 * a0 + a1 * a1 + a2 * a2;
            }
        }
    s1 += __shfl_xor(s1, 16, 64); s1 += __shfl_xor(s1, 32, 64);
    s2 += __shfl_xor(s2, 16, 64); s2 += __shfl_xor(s2, 32, 64);
    float mu = s1 * (1.f / 384.f);
    float var = s2 * (1.f / 384.f) - mu * mu;
    float rs = rsqrtf(var + EPSV);

    // ---- precompute fp16 gate for this lane's 96 cols, indexed [ck=s*4+m] ----
    f16x8 gate[12];
    #pragma unroll
    for (int s = 0; s < 3; ++s)
        #pragma unroll
        for (int m = 0; m < 4; ++m) {
            H8 gg;
            #pragma unroll
            for (int nt = 0; nt < 2; ++nt) {
                int q8 = m * 2 + nt;
                int cc = m * 32 + nt * 16 + g * 4;
                int col = s * 128 + cc;
                F4 lg = *(const F4*)(lag + col);
                F4 lb = *(const F4*)(lab + col);
                f16x4 sv = (s == 0) ? kiv[q8] : (s == 1) ? kjv[q8] : ev[q8];
                #pragma unroll
                for (int i = 0; i < 4; ++i) {
                    float a = (float)qv[q8][i] * (float)sv[i] * ISQ;
                    float z = (a - mu) * rs * lg.v[i] + lb.v[i];
                    gg.h[nt * 4 + i] = (_Float16)(1.f / (1.f + expf(-z)));
                }
            }
            gate[s * 4 + m] = gg.h;
        }

    const _Float16* p1p = p12 + ((size_t)nd * 4 + hh) * 768;
    const _Float16* p2p = p12 + ((size_t)ns * 4 + hh) * 768 + 384;
    const int laneA = ((g & 1) << 5) + c;   // src lane for k=8g..8g+3
    const int laneB = laneA + 16;           // src lane for k=8g+4..8g+7
    const bool hi = (g >> 1) != 0;

    // ---- main loop: 12 chunks of 32 cols; fully unrolled, no barriers ----
    f32x4 acc2[8] = {};
    #pragma unroll
    for (int ck = 0; ck < 12; ++ck) {
        H4 pa0, pa1, pb0, pb1;
        pa0.h = *(const f16x4*)(p1p + ck * 32 + g * 4);
        pa1.h = *(const f16x4*)(p1p + ck * 32 + 16 + g * 4);
        pb0.h = *(const f16x4*)(p2p + ck * 32 + g * 4);
        pb1.h = *(const f16x4*)(p2p + ck * 32 + 16 + g * 4);
        F4 bm0 = *(const F4*)(bm + ck * 32 + g * 4);
        F4 bm1 = *(const F4*)(bm + ck * 32 + 16 + g * 4);

        // P3 (swapped): lane gets P3[own row][ck*32 + nt*16 + 4g + i]
        f32x4 a3[2] = {};
        #pragma unroll
        for (int ks = 0; ks < 4; ++ks)
            #pragma unroll
            for (int nt = 0; nt < 2; ++nt) {
                f16x8 awm = *(const f16x8*)(wm3T + (size_t)(ck * 32 + nt * 16 + c) * 128 + ks * 32 + g * 8);
                a3[nt] = __builtin_amdgcn_mfma_f32_16x16x32_f16(awm, af3[ks], a3[nt], 0, 0, 0);
            }

        // t-build (lane-local)
        H4 t0, t1;
        #pragma unroll
        for (int i = 0; i < 4; ++i) {
            float v0 = ((float)pa0.h[i] + (float)pb0.h[i] + a3[0][i] + bm0.v[i]) * (float)gate[ck][i];
            float v1 = ((float)pa1.h[i] + (float)pb1.h[i] + a3[1][i] + bm1.v[i]) * (float)gate[ck][4 + i];
            t0.h[i] = (_Float16)v0;
            t1.h[i] = (_Float16)v1;
        }

        // in-wave exchange: build GEMM2 B-frag bt[j] = t[own row][k = g*8 + j]
        int a0x = __shfl((int)t0.u.x, laneA, 64);
        int a0y = __shfl((int)t0.u.y, laneA, 64);
        int a1x = __shfl((int)t1.u.x, laneA, 64);
        int a1y = __shfl((int)t1.u.y, laneA, 64);
        int b0x = __shfl((int)t0.u.x, laneB, 64);
        int b0y = __shfl((int)t0.u.y, laneB, 64);
        int b1x = __shfl((int)t1.u.x, laneB, 64);
        int b1y = __shfl((int)t1.u.y, laneB, 64);
        H8 bt;
        bt.u.x = (unsigned)(hi ? a1x : a0x);
        bt.u.y = (unsigned)(hi ? a1y : a0y);
        bt.u.z = (unsigned)(hi ? b1x : b0x);
        bt.u.w = (unsigned)(hi ? b1y : b0y);

        // GEMM2 (swapped): lane accumulates u[own row][ni*16 + 4g + i]
        #pragma unroll
        for (int ni = 0; ni < 8; ++ni) {
            f16x8 awg = *(const f16x8*)(wmsgT + (size_t)(ni * 16 + c) * 384 + ck * 32 + g * 8);
            acc2[ni] = __builtin_amdgcn_mfma_f32_16x16x32_f16(awg, bt.h, acc2[ni], 0, 0, 0);
        }
    }

    // ---- epilogue: +bmsg, row-LN(128) via shfl, scatter-add ----
    float u[8][4];
    float e1 = 0.f, e2 = 0.f;
    #pragma unroll
    for (int ni = 0; ni < 8; ++ni) {
        F4 bz = *(const F4*)(bmsg + ni * 16 + g * 4);
        #pragma unroll
        for (int i = 0; i < 4; ++i) {
            u[ni][i] = acc2[ni][i] + bz.v[i];
            e1 += u[ni][i]; e2 += u[ni][i] * u[ni][i];
        }
    }
    e1 += __shfl_xor(e1, 16, 64); e1 += __shfl_xor(e1, 32, 64);
    e2 += __shfl_xor(e2, 16, 64); e2 += __shfl_xor(e2, 32, 64);
    float mu2 = e1 * (1.f / 128.f);
    float var2 = e2 * (1.f / 128.f) - mu2 * mu2;
    float rs2 = rsqrtf(var2 + EPSV);
    float* ap = agg + (size_t)nd * HC_ + hh * CC_;
    #pragma unroll
    for (int ni = 0; ni < 8; ++ni) {
        F4 lg = *(const F4*)(lmg + ni * 16 + g * 4);
        F4 lb = *(const F4*)(lmb + ni * 16 + g * 4);
        #pragma unroll
        for (int i = 0; i < 4; ++i) {
            float msg = (u[ni][i] - mu2) * rs2 * lg.v[i] + lb.v[i];
            atomicAdd(ap + ni * 16 + g * 4 + i, msg);
        }
    }
}

// ---------------- BN stats over nodes (per channel) ----------------
__global__ void bn_stats_kernel(const float* __restrict__ outb,
                                float* __restrict__ mu, float* __restrict__ rv)
{
    int c = blockIdx.x;
    int tid = threadIdx.x;
    float s = 0.f, s2 = 0.f;
    for (int r = tid; r < N_NODES; r += 256) {
        float x = outb[(size_t)r * CC_ + c];
        s += x; s2 += x * x;
    }
    #pragma unroll
    for (int off = 1; off < 64; off <<= 1) {
        s += __shfl_xor(s, off);
        s2 += __shfl_xor(s2, off);
    }
    __shared__ float ls[8];
    int w = tid >> 6, ln = tid & 63;
    if (ln == 0) { ls[w] = s; ls[4 + w] = s2; }
    __syncthreads();
    if (tid == 0) {
        float S = ls[0] + ls[1] + ls[2] + ls[3];
        float S2 = ls[4] + ls[5] + ls[6] + ls[7];
        float m = S * (1.f / N_NODES);
        float var = S2 * (1.f / N_NODES) - m * m;
        mu[c] = m;
        rv[c] = rsqrtf(var + EPSV);
    }
}

// ---------------- BN apply + silu + residual(skip) -> h16 ----------------
__global__ void bn_apply_kernel(const float* __restrict__ outb, const _Float16* __restrict__ qkvs,
                                const float* __restrict__ mu, const float* __restrict__ rv,
                                const float* __restrict__ g, const float* __restrict__ b,
                                _Float16* __restrict__ h16)
{
    int idx = blockIdx.x * 256 + threadIdx.x;
    int n = idx >> 7, c = idx & (CC_ - 1);
    float x = (outb[idx] - mu[c]) * rv[c] * g[c] + b[c];
    x = x / (1.f + expf(-x));
    float skip = (float)qkvs[(size_t)n * 1664 + 1536 + c];
    h16[idx] = (_Float16)(x + skip);
}

// ---------------- output head + batch correction ----------------
__global__ void head_kernel(const float* __restrict__ feat, const float* __restrict__ fcow,
                            const float* __restrict__ fcob, const int* __restrict__ batch,
                            float* __restrict__ out, float* __restrict__ qa_buf,
                            float* __restrict__ qsum, float* __restrict__ cnt)
{
    int n = blockIdx.x * 256 + threadIdx.x;
    float ea = fcob[0], qa = fcob[1];
    for (int j = 0; j < DD; ++j) {
        float f = feat[(size_t)n * DD + j];
        ea += f * fcow[2 * j];
        qa += f * fcow[2 * j + 1];
    }
    out[2 * n] = ea;
    qa_buf[n] = qa;
    int b = batch[n];
    atomicAdd(&qsum[b], qa);
    atomicAdd(&cnt[b], 1.0f);
}

__global__ void final_kernel(const float* __restrict__ qa_buf, const int* __restrict__ batch,
                             const float* __restrict__ qsum, const float* __restrict__ cnt,
                             float* __restrict__ out)
{
    int n = blockIdx.x * 256 + threadIdx.x;
    int b = batch[n];
    out[2 * n + 1] = qa_buf[n] - qsum[b] / cnt[b];
}

// ---------------- launcher ----------------
extern "C" void kernel_launch(void* const* d_in, const int* in_sizes, int n_in,
                              void* d_out, int out_size, void* d_ws, size_t ws_size,
                              hipStream_t stream)
{
    const float* x         = (const float*)d_in[0];
    const float* edge_attr = (const float*)d_in[1];
    const int*   edge_index= (const int*)d_in[2];
    const int*   batch     = (const int*)d_in[3];
    const float* rbf_b1 = (const float*)d_in[7];
    const float* rbf_b2 = (const float*)d_in[9];
    const float* bcat = (const float*)d_in[18];
    const float* bm = (const float*)d_in[20];
    const float* lag = (const float*)d_in[21];
    const float* lab = (const float*)d_in[22];
    const float* bmsg = (const float*)d_in[24];
    const float* lmg = (const float*)d_in[25];
    const float* lmb = (const float*)d_in[26];
    const float* bn_g = (const float*)d_in[27];
    const float* bn_b = (const float*)d_in[28];
    const float* fc_b = (const float*)d_in[32];
    const float* fco_w = (const float*)d_in[33];
    const float* fco_b = (const float*)d_in[34];

    const int* src = edge_index;
    const int* dst = edge_index + NE;

    char* base = (char*)d_ws;
    size_t off = 0;
    auto alloc = [&](size_t bytes) -> char* {
        char* p = base + off;
        off += (bytes + 255) & ~(size_t)255;
        return p;
    };
    _Float16* wbuf   = (_Float16*)alloc((size_t)TOT_H * 2);
    float*    biasb  = (float*)alloc((size_t)5 * 1664 * 4);
    _Float16* x16    = (_Float16*)alloc((size_t)N_NODES * 96 * 2);
    _Float16* h16    = (_Float16*)alloc((size_t)N_NODES * DD * 2);
    _Float16* rbf16  = (_Float16*)alloc((size_t)NE * DD * 2);
    _Float16* tmp16  = (_Float16*)alloc((size_t)NE * DD * 2);
    _Float16* ef16   = (_Float16*)alloc((size_t)NE * DD * 2);
    _Float16* qkvs16 = (_Float16*)alloc((size_t)N_NODES * 1664 * 2);
    _Float16* ebuf16 = (_Float16*)alloc((size_t)NE * HC_ * 2);
    _Float16* p12    = (_Float16*)alloc((size_t)8192 * 768 * 2);
    float* agg    = (float*)alloc((size_t)N_NODES * HC_ * 4);
    float* outb   = (float*)alloc((size_t)N_NODES * CC_ * 4);
    float* featb  = (float*)alloc((size_t)N_NODES * DD * 4);
    float* qa_buf = (float*)alloc((size_t)N_NODES * 4);
    float* mu     = (float*)alloc(CC_ * 4);
    float* rv     = (float*)alloc(CC_ * 4);
    float* qsum   = (float*)alloc((size_t)NB * 2 * 4);
    float* cnt    = qsum + NB;

    // ---- weight prep (all layers) + input packs ----
    wprep_kernel<<<(TOT_ALL + 255) / 256, 256, 0, stream>>>(
        (const float*)d_in[10], (const float*)d_in[11], (const float*)d_in[12], (const float*)d_in[13],
        (const float*)d_in[14], (const float*)d_in[15], (const float*)d_in[29], (const float*)d_in[30],
        (const float*)d_in[19], (const float*)d_in[23], (const float*)d_in[16], (const float*)d_in[17],
        (const float*)d_in[4], (const float*)d_in[6], (const float*)d_in[8], (const float*)d_in[31],
        wbuf, biasb);
    xpack_kernel<<<(N_NODES * 96 + 255) / 256, 256, 0, stream>>>(x, x16);
    rbf_kernel<<<(NE * 128) / 256, 256, 0, stream>>>(edge_attr, rbf16);

    // h = x @ emb + emb_b  (K=96 zero-padded)
    gemm16<0, 0, false, false><<<dim3(16, 1), 256, 0, stream>>>(
        x16, 96, wbuf + OFF_EMBT, 96, 0, (const float*)d_in[5], h16, DD, 96);
    // ef = softplus(rbf@w1+b1) @ w2 + b2
    gemm16<0, 1, false, false><<<dim3(NE / 128, 1), 256, 0, stream>>>(
        rbf16, 128, wbuf + OFF_W1T, 128, 0, rbf_b1, tmp16, 128, 128);
    gemm16<0, 0, false, false><<<dim3(NE / 128, 1), 256, 0, stream>>>(
        tmp16, 128, wbuf + OFF_W2T, 128, 0, rbf_b2, ef16, 128, 128);

    for (int l = 0; l < NL; ++l) {
        const _Float16* lw = wbuf + (size_t)l * LWH;
        const float* bias_l = biasb + (size_t)l * 1664;
        const float* bcat_l = bcat + (size_t)l * CC_;
        const float* bm_l = bm + (size_t)l * C3_;
        const float* lag_l = lag + (size_t)l * C3_;
        const float* lab_l = lab + (size_t)l * C3_;
        const float* bmsg_l = bmsg + (size_t)l * CC_;
        const float* lmg_l = lmg + (size_t)l * CC_;
        const float* lmb_l = lmb + (size_t)l * CC_;
        const float* bng_l = bn_g + (size_t)l * CC_;
        const float* bnb_l = bn_b + (size_t)l * CC_;

        // qkvs = h @ [wq|wk|wv|wskip] + [bq|bk|bv|bskip]
        gemm16<0, 0, false, false><<<dim3(16, 13), 256, 0, stream>>>(
            h16, DD, lw + OFF_QKVST, 128, 0, bias_l, qkvs16, 1664, 128);
        // e = ef @ we
        gemm16<0, 0, false, false><<<dim3(NE / 128, 4), 256, 0, stream>>>(
            ef16, 128, lw + OFF_WET, 128, 0, nullptr, ebuf16, HC_, 128);
        // P1|P2 = v @ [wm_top | wm_mid]
        gemm16<2, 0, false, false><<<dim3(64, 6), 256, 0, stream>>>(
            qkvs16 + 1024, 1664, lw + OFF_W12T, 128, 0, nullptr, p12, 768, 128);

        // fused: P3 + gate + GEMM2 + row-LN + segment scatter (zero-LDS version)
        hipMemsetAsync(agg, 0, (size_t)N_NODES * HC_ * sizeof(float), stream);
        fused_edge_kernel<<<NE * HH_ / 64, 256, 0, stream>>>(
            qkvs16, ebuf16, p12, lw + OFF_WM3T, lw + OFF_WMSGT,
            bm_l, lag_l, lab_l, bmsg_l, lmg_l, lmb_l, src, dst, agg);

        // outb = agg @ wcat + bcat (split-K), BN, silu, +skip -> h16
        hipMemsetAsync(outb, 0, (size_t)N_NODES * CC_ * sizeof(float), stream);
        gemm16<1, 0, false, true><<<dim3(16, 1, 4), 256, 0, stream>>>(
            agg, HC_, lw + OFF_WCATT, 512, 0, bcat_l, outb, CC_, 512);
        bn_stats_kernel<<<CC_, 256, 0, stream>>>(outb, mu, rv);
        bn_apply_kernel<<<(N_NODES * CC_) / 256, 256, 0, stream>>>(
            outb, qkvs16, mu, rv, bng_l, bnb_l, h16);
    }

    // feat = silu(h @ fc_w + fc_b)
    gemm16<0, 2, true, false><<<dim3(16, 1), 256, 0, stream>>>(
        h16, DD, wbuf + OFF_FCT, 128, 0, fc_b, featb, DD, 128);

    hipMemsetAsync(qsum, 0, (size_t)NB * 2 * sizeof(float), stream);
    head_kernel<<<N_NODES / 256, 256, 0, stream>>>(featb, fco_w, fco_b, batch,
                                                   (float*)d_out, qa_buf, qsum, cnt);
    final_kernel<<<N_NODES / 256, 256, 0, stream>>>(qa_buf, batch, qsum, cnt, (float*)d_out);
}

// Round 8
// 1139.478 us; speedup vs baseline: 1.5243x; 1.5243x over previous
//
#include <hip/hip_runtime.h>
#include <math.h>

#define N_NODES 2048
#define NE      16384
#define NB      64
#define FIN     92
#define DD      128
#define HH_     4
#define CC_     128
#define HC_     512
#define C3_     384
#define NL      5
#define EPSV    1e-5f

// per-layer packed fp16 weight block offsets (halves)
#define LWH        540672
#define OFF_QKVST  0        // [1664][128]
#define OFF_W12T   212992   // [768][128]
#define OFF_WM3T   311296   // [384][128]
#define OFF_WMSGT  360448   // [128][384]
#define OFF_WET    409600   // [512][128]
#define OFF_WCATT  475136   // [128][512]
#define EX0        (5*LWH)
#define OFF_EMBT   (EX0)            // [128][96]
#define OFF_W1T    (EX0+12288)      // [128][128]
#define OFF_W2T    (EX0+28672)      // [128][128]
#define OFF_FCT    (EX0+45056)      // [128][128]
#define TOT_H      (EX0+61440)
#define TOT_ALL    (TOT_H + 5*1664)

struct alignas(16) F4 { float v[4]; };
typedef _Float16 f16x8 __attribute__((ext_vector_type(8)));
typedef float f32x4 __attribute__((ext_vector_type(4)));
union H8 { f16x8 h; uint4 u; };

// ---------------- weight prep: transpose + fp16 convert, all layers ----------------
__global__ void wprep_kernel(const float* __restrict__ wq, const float* __restrict__ bq,
                             const float* __restrict__ wk, const float* __restrict__ bk,
                             const float* __restrict__ wv, const float* __restrict__ bv,
                             const float* __restrict__ wskip, const float* __restrict__ bskip,
                             const float* __restrict__ wm, const float* __restrict__ wmsg,
                             const float* __restrict__ we, const float* __restrict__ wcat,
                             const float* __restrict__ emb_w, const float* __restrict__ rbf_w1,
                             const float* __restrict__ rbf_w2, const float* __restrict__ fc_w,
                             _Float16* __restrict__ wb, float* __restrict__ bb)
{
    int idx = blockIdx.x * 256 + threadIdx.x;
    if (idx < 5 * LWH) {
        int l = idx / LWH, r = idx % LWH;
        float val;
        if (r < 212992) {
            int n = r >> 7, kk = r & 127;
            if (n < 512)       val = wq[(size_t)l * 65536 + kk * 512 + n];
            else if (n < 1024) val = wk[(size_t)l * 65536 + kk * 512 + (n - 512)];
            else if (n < 1536) val = wv[(size_t)l * 65536 + kk * 512 + (n - 1024)];
            else               val = wskip[(size_t)l * 16384 + kk * 128 + (n - 1536)];
        } else if (r < 311296) {
            int t = r - 212992; int n = t >> 7, kk = t & 127;
            val = (n < 384) ? wm[(size_t)l * 147456 + kk * 384 + n]
                            : wm[(size_t)l * 147456 + (128 + kk) * 384 + (n - 384)];
        } else if (r < 360448) {
            int t = r - 311296; int n = t >> 7, kk = t & 127;
            val = wm[(size_t)l * 147456 + (256 + kk) * 384 + n];
        } else if (r < 409600) {
            int t = r - 360448; int n = t / 384, kk = t % 384;
            val = wmsg[(size_t)l * 49152 + kk * 128 + n];
        } else if (r < 475136) {
            int t = r - 409600; int n = t >> 7, kk = t & 127;
            val = we[(size_t)l * 65536 + kk * 512 + n];
        } else {
            int t = r - 475136; int n = t >> 9, kk = t & 511;
            val = wcat[(size_t)l * 65536 + kk * 128 + n];
        }
        wb[idx] = (_Float16)val;
    } else if (idx < TOT_H) {
        int t = idx - EX0;
        float val;
        if (t < 12288)      { int n = t / 96, kk = t % 96; val = (kk < FIN) ? emb_w[kk * 128 + n] : 0.f; }
        else if (t < 28672) { int t2 = t - 12288; int n = t2 >> 7, kk = t2 & 127; val = rbf_w1[kk * 128 + n]; }
        else if (t < 45056) { int t2 = t - 28672; int n = t2 >> 7, kk = t2 & 127; val = rbf_w2[kk * 128 + n]; }
        else                { int t2 = t - 45056; int n = t2 >> 7, kk = t2 & 127; val = fc_w[kk * 128 + n]; }
        wb[idx] = (_Float16)val;
    } else if (idx < TOT_ALL) {
        int t = idx - TOT_H;
        int l = t / 1664, n = t % 1664;
        float val;
        if (n < 512)       val = bq[l * 512 + n];
        else if (n < 1024) val = bk[l * 512 + n - 512];
        else if (n < 1536) val = bv[l * 512 + n - 1024];
        else               val = bskip[l * 128 + n - 1536];
        bb[t] = val;
    }
}

// ---------------- x -> fp16 padded to 96 ----------------
__global__ void xpack_kernel(const float* __restrict__ x, _Float16* __restrict__ x16)
{
    int idx = blockIdx.x * 256 + threadIdx.x;
    if (idx >= N_NODES * 96) return;
    int n = idx / 96, kk = idx % 96;
    x16[idx] = (kk < FIN) ? (_Float16)x[n * FIN + kk] : (_Float16)0.f;
}

// ---------------- RBF expansion (fp16 out) ----------------
__global__ void rbf_kernel(const float* __restrict__ eattr, _Float16* __restrict__ rbf)
{
    int idx = blockIdx.x * 256 + threadIdx.x;
    int e = idx >> 7, c = idx & 127;
    float x0 = eattr[e * 3 + 0], x1 = eattr[e * 3 + 1], x2 = eattr[e * 3 + 2];
    float d = sqrtf(x0 * x0 + x1 * x1 + x2 * x2);
    float ctr = (8.0f / 127.0f) * (float)c;
    float t = d - ctr;
    rbf[idx] = (_Float16)expf(-15.875f * t * t);
}

// ---------------- unified fp16 MFMA GEMM ----------------
template<int AMODE, int ACT, bool OUT_F32, bool SPLITK>
__global__ __launch_bounds__(256) void gemm16(
    const void* __restrict__ Av, int lda,
    const _Float16* __restrict__ Bt, int ldb, int bkoff,
    const float* __restrict__ bias,
    void* __restrict__ Cv, int ldc, int K)
{
    __shared__ alignas(16) _Float16 As[128 * 40];
    __shared__ alignas(16) _Float16 Bs[128 * 40];
    const int tid = threadIdx.x;
    const int w = tid >> 6, l = tid & 63;
    const int g = l >> 4, c = l & 15;
    const int row0 = blockIdx.x * 128;
    const int col0 = blockIdx.y * 128;
    int k0 = 0, kend = K;
    if (SPLITK) { int ks = K / gridDim.z; k0 = blockIdx.z * ks; kend = k0 + ks; }
    f32x4 acc[2][8] = {};
    for (int kb = k0; kb < kend; kb += 32) {
        __syncthreads();
        #pragma unroll
        for (int i = 0; i < 2; ++i) {
            int p = tid + 256 * i;
            int r = p >> 2, q = p & 3;
            *(uint4*)&Bs[r * 40 + q * 8] =
                *(const uint4*)&Bt[(size_t)(col0 + r) * ldb + bkoff + kb + q * 8];
            if (AMODE == 1) {
                const float* Af = (const float*)Av;
                const float* ap = Af + (size_t)(row0 + r) * lda + kb + q * 8;
                F4 x0 = *(const F4*)ap;
                F4 x1 = *(const F4*)(ap + 4);
                union { _Float16 h[8]; uint4 u; } cv;
                #pragma unroll
                for (int j = 0; j < 4; ++j) { cv.h[j] = (_Float16)x0.v[j]; cv.h[4 + j] = (_Float16)x1.v[j]; }
                *(uint4*)&As[r * 40 + q * 8] = cv.u;
            } else if (AMODE == 2) {
                const _Float16* Ah = (const _Float16*)Av;
                int row = row0 + r;
                *(uint4*)&As[r * 40 + q * 8] =
                    *(const uint4*)&Ah[(size_t)(row >> 2) * lda + (row & 3) * 128 + kb + q * 8];
            } else {
                const _Float16* Ah = (const _Float16*)Av;
                *(uint4*)&As[r * 40 + q * 8] =
                    *(const uint4*)&Ah[(size_t)(row0 + r) * lda + kb + q * 8];
            }
        }
        __syncthreads();
        f16x8 af[2], bf[8];
        #pragma unroll
        for (int mi = 0; mi < 2; ++mi)
            af[mi] = *(const f16x8*)&As[(w * 32 + mi * 16 + c) * 40 + g * 8];
        #pragma unroll
        for (int ni = 0; ni < 8; ++ni)
            bf[ni] = *(const f16x8*)&Bs[(ni * 16 + c) * 40 + g * 8];
        #pragma unroll
        for (int mi = 0; mi < 2; ++mi)
            #pragma unroll
            for (int ni = 0; ni < 8; ++ni)
                acc[mi][ni] = __builtin_amdgcn_mfma_f32_16x16x32_f16(af[mi], bf[ni], acc[mi][ni], 0, 0, 0);
    }
    const bool addb = bias && (!SPLITK || blockIdx.z == 0);
    #pragma unroll
    for (int mi = 0; mi < 2; ++mi)
        #pragma unroll
        for (int ni = 0; ni < 8; ++ni)
            #pragma unroll
            for (int i = 0; i < 4; ++i) {
                int row = row0 + w * 32 + mi * 16 + g * 4 + i;
                int col = col0 + ni * 16 + c;
                float v = acc[mi][ni][i] + (addb ? bias[col] : 0.f);
                if (ACT == 1) v = fmaxf(v, 0.f) + log1pf(expf(-fabsf(v)));
                else if (ACT == 2) v = v / (1.f + expf(-v));
                if (SPLITK)       atomicAdd((float*)Cv + (size_t)row * ldc + col, v);
                else if (OUT_F32) ((float*)Cv)[(size_t)row * ldc + col] = v;
                else              ((_Float16*)Cv)[(size_t)row * ldc + col] = (_Float16)v;
            }
}

// ---------------- fused edge kernel v3: LDS-staged GEMMs, register gate ----------------
// Per block: 16 edges = 64 edge-head rows, 4 waves. Gate precomputed into
// registers (phase 1, no LDS staging of q/k/e); P3 + t-build + GEMM2 via small
// LDS panels as in the verified round-6 kernel.
#define EB2 16
#define RW2 64

__global__ __launch_bounds__(256, 3) void fused_edge_kernel(
    const _Float16* __restrict__ qkvs,   // [2048][1664]
    const _Float16* __restrict__ e16,    // [65536][128]
    const _Float16* __restrict__ p12,    // [8192][768]
    const _Float16* __restrict__ wm3T,   // [384][128]
    const _Float16* __restrict__ wmsgT,  // [128][384]
    const float* __restrict__ bm, const float* __restrict__ lag, const float* __restrict__ lab,
    const float* __restrict__ bmsg, const float* __restrict__ lmg, const float* __restrict__ lmb,
    const int* __restrict__ src, const int* __restrict__ dst,
    float* __restrict__ agg)
{
    __shared__ alignas(16) _Float16 St [RW2 * 40];   // p3 chunk -> t chunk
    __shared__ alignas(16) _Float16 Bs3[32 * 136];
    __shared__ alignas(16) _Float16 Bsg[128 * 40];
    __shared__ int dstn[EB2], srcn[EB2];

    const int tid = threadIdx.x;
    const int w = tid >> 6, l = tid & 63;
    const int g = l >> 4, c = l & 15;
    const int e0 = blockIdx.x * EB2;
    const int row0 = blockIdx.x * RW2;
    const float ISQ = 0.05103103630798287f;  // 1/sqrt(384)

    if (tid < EB2) { dstn[tid] = dst[e0 + tid]; srcn[tid] = src[e0 + tid]; }
    __syncthreads();

    // P3 A-fragments: e rows contiguous; reused for every chunk. (row = row0+w*16+c)
    f16x8 af3[4];
    {
        const _Float16* ep = e16 + (size_t)(row0 + w * 16 + c) * 128;
        #pragma unroll
        for (int ks = 0; ks < 4; ++ks) af3[ks] = *(const f16x8*)(ep + ks * 32 + g * 8);
    }

    // ---- phase 1: per-thread alpha -> LN stats -> gate (all in registers) ----
    // Thread owns row r_own = tid>>2, cols {ck*32 + cp*8 .. +8} for ck=0..11.
    const int r_own = tid >> 2, cp = tid & 3;
    const int edge_o = r_own >> 2, hh_o = r_own & 3;
    const int nd_o = dstn[edge_o], ns_o = srcn[edge_o];
    const _Float16* qpo  = qkvs + (size_t)nd_o * 1664 + hh_o * 128;
    const _Float16* kipo = qkvs + (size_t)nd_o * 1664 + 512 + hh_o * 128;
    const _Float16* kjpo = qkvs + (size_t)ns_o * 1664 + 512 + hh_o * 128;
    const _Float16* epo  = e16 + (size_t)(row0 + r_own) * 128;
    const _Float16* p1p  = p12 + ((size_t)nd_o * 4 + hh_o) * 768;
    const _Float16* p2p  = p12 + ((size_t)ns_o * 4 + hh_o) * 768 + 384;

    f16x8 gate[12];   // holds alpha first, then gate in place
    {
        f16x8 q4[4];
        #pragma unroll
        for (int m = 0; m < 4; ++m) q4[m] = *(const f16x8*)(qpo + cp * 8 + 32 * m);
        float s1 = 0.f, s2 = 0.f;
        #pragma unroll
        for (int ck = 0; ck < 12; ++ck) {
            int s = ck >> 2, m = ck & 3;
            const _Float16* kp = (s == 0) ? kipo : (s == 1) ? kjpo : epo;
            f16x8 kv = *(const f16x8*)(kp + cp * 8 + 32 * m);
            H8 av;
            #pragma unroll
            for (int j = 0; j < 8; ++j) {
                float a = (float)q4[m][j] * (float)kv[j] * ISQ;
                s1 += a; s2 += a * a;
                av.h[j] = (_Float16)a;
            }
            gate[ck] = av.h;
        }
        s1 += __shfl_xor(s1, 1, 64); s1 += __shfl_xor(s1, 2, 64);
        s2 += __shfl_xor(s2, 1, 64); s2 += __shfl_xor(s2, 2, 64);
        float mu = s1 * (1.f / 384.f);
        float var = s2 * (1.f / 384.f) - mu * mu;
        float rs = rsqrtf(var + EPSV);
        #pragma unroll
        for (int ck = 0; ck < 12; ++ck) {
            int col0c = ck * 32 + cp * 8;
            F4 lg0 = *(const F4*)(lag + col0c), lg1 = *(const F4*)(lag + col0c + 4);
            F4 lb0 = *(const F4*)(lab + col0c), lb1 = *(const F4*)(lab + col0c + 4);
            H8 gg; gg.h = gate[ck];
            #pragma unroll
            for (int j = 0; j < 8; ++j) {
                float lgv = (j < 4) ? lg0.v[j] : lg1.v[j - 4];
                float lbv = (j < 4) ? lb0.v[j] : lb1.v[j - 4];
                float z = ((float)gg.h[j] - mu) * rs * lgv + lbv;
                gg.h[j] = (_Float16)(1.f / (1.f + __expf(-z)));
            }
            gate[ck] = gg.h;
        }
    }

    // ---- chunk loop over K=384 in 32-col chunks (unrolled: gate[ck] static) ----
    f32x4 acc2[8] = {};
    #pragma unroll
    for (int ck = 0; ck < 12; ++ck) {
        __syncthreads();   // prior GEMM2 done reading Bsg/St
        // stage B panels (L2-hot weights)
        #pragma unroll
        for (int i = 0; i < 2; ++i) {
            int p = tid + 256 * i;
            int col = p >> 4, q8 = p & 15;
            *(f16x8*)&Bs3[col * 136 + q8 * 8] =
                *(const f16x8*)&wm3T[(size_t)(ck * 32 + col) * 128 + q8 * 8];
        }
        #pragma unroll
        for (int i = 0; i < 2; ++i) {
            int p = tid + 256 * i;
            int col = p >> 2, q4i = p & 3;
            *(f16x8*)&Bsg[col * 40 + q4i * 8] =
                *(const f16x8*)&wmsgT[(size_t)col * 384 + ck * 32 + q4i * 8];
        }
        __syncthreads();

        // P3 chunk: wave w -> rows w*16.., 32 cols
        f32x4 a3[2] = {};
        #pragma unroll
        for (int ks = 0; ks < 4; ++ks)
            #pragma unroll
            for (int nt = 0; nt < 2; ++nt) {
                f16x8 bf = *(const f16x8*)&Bs3[(nt * 16 + c) * 136 + ks * 32 + g * 8];
                a3[nt] = __builtin_amdgcn_mfma_f32_16x16x32_f16(af3[ks], bf, a3[nt], 0, 0, 0);
            }
        #pragma unroll
        for (int nt = 0; nt < 2; ++nt)
            #pragma unroll
            for (int i = 0; i < 4; ++i)
                St[(w * 16 + g * 4 + i) * 40 + nt * 16 + c] = (_Float16)a3[nt][i];
        __syncthreads();

        // t-build in place (gate from registers)
        {
            int kk0 = ck * 32 + cp * 8;
            f16x8 p1v = *(const f16x8*)(p1p + kk0);
            f16x8 p2v = *(const f16x8*)(p2p + kk0);
            f16x8 p3v = *(const f16x8*)&St[r_own * 40 + cp * 8];
            F4 bm0 = *(const F4*)(bm + kk0), bm1 = *(const F4*)(bm + kk0 + 4);
            f16x8 gv = gate[ck];
            H8 tv;
            #pragma unroll
            for (int j = 0; j < 8; ++j) {
                float bmv = (j < 4) ? bm0.v[j] : bm1.v[j - 4];
                float t = (float)p1v[j] + (float)p2v[j] + (float)p3v[j] + bmv;
                tv.h[j] = (_Float16)(t * (float)gv[j]);
            }
            *(f16x8*)&St[r_own * 40 + cp * 8] = tv.h;
        }
        __syncthreads();

        // GEMM2 accumulate: wave w -> rows w*16.., all 8 n-tiles
        {
            f16x8 af2 = *(const f16x8*)&St[(w * 16 + c) * 40 + g * 8];
            #pragma unroll
            for (int ni = 0; ni < 8; ++ni) {
                f16x8 bf = *(const f16x8*)&Bsg[(ni * 16 + c) * 40 + g * 8];
                acc2[ni] = __builtin_amdgcn_mfma_f32_16x16x32_f16(af2, bf, acc2[ni], 0, 0, 0);
            }
        }
    }

    // ---- epilogue: +bmsg, row-LN(128), scatter-add (rows w*16 + g*4 + i) ----
    float bz[8], lgv2[8], lbv2[8];
    #pragma unroll
    for (int ni = 0; ni < 8; ++ni) {
        int colc = ni * 16 + c;
        bz[ni] = bmsg[colc]; lgv2[ni] = lmg[colc]; lbv2[ni] = lmb[colc];
    }
    #pragma unroll
    for (int i = 0; i < 4; ++i) {
        float u[8];
        float s1 = 0.f, s2 = 0.f;
        #pragma unroll
        for (int ni = 0; ni < 8; ++ni) {
            u[ni] = acc2[ni][i] + bz[ni];
            s1 += u[ni]; s2 += u[ni] * u[ni];
        }
        #pragma unroll
        for (int off = 1; off < 16; off <<= 1) {
            s1 += __shfl_xor(s1, off);
            s2 += __shfl_xor(s2, off);
        }
        float mu = s1 * (1.f / 128.f);
        float var = s2 * (1.f / 128.f) - mu * mu;
        float rs = rsqrtf(var + EPSV);
        int r = w * 16 + g * 4 + i;
        int el = r >> 2, hh = r & 3;
        int nd = dstn[el];
        float* ap = agg + (size_t)nd * HC_ + hh * CC_;
        #pragma unroll
        for (int ni = 0; ni < 8; ++ni) {
            float msg = (u[ni] - mu) * rs * lgv2[ni] + lbv2[ni];
            atomicAdd(ap + ni * 16 + c, msg);
        }
    }
}

// ---------------- BN stats over nodes (per channel) ----------------
__global__ void bn_stats_kernel(const float* __restrict__ outb,
                                float* __restrict__ mu, float* __restrict__ rv)
{
    int c = blockIdx.x;
    int tid = threadIdx.x;
    float s = 0.f, s2 = 0.f;
    for (int r = tid; r < N_NODES; r += 256) {
        float x = outb[(size_t)r * CC_ + c];
        s += x; s2 += x * x;
    }
    #pragma unroll
    for (int off = 1; off < 64; off <<= 1) {
        s += __shfl_xor(s, off);
        s2 += __shfl_xor(s2, off);
    }
    __shared__ float ls[8];
    int w = tid >> 6, ln = tid & 63;
    if (ln == 0) { ls[w] = s; ls[4 + w] = s2; }
    __syncthreads();
    if (tid == 0) {
        float S = ls[0] + ls[1] + ls[2] + ls[3];
        float S2 = ls[4] + ls[5] + ls[6] + ls[7];
        float m = S * (1.f / N_NODES);
        float var = S2 * (1.f / N_NODES) - m * m;
        mu[c] = m;
        rv[c] = rsqrtf(var + EPSV);
    }
}

// ---------------- BN apply + silu + residual(skip) -> h16 ----------------
__global__ void bn_apply_kernel(const float* __restrict__ outb, const _Float16* __restrict__ qkvs,
                                const float* __restrict__ mu, const float* __restrict__ rv,
                                const float* __restrict__ g, const float* __restrict__ b,
                                _Float16* __restrict__ h16)
{
    int idx = blockIdx.x * 256 + threadIdx.x;
    int n = idx >> 7, c = idx & (CC_ - 1);
    float x = (outb[idx] - mu[c]) * rv[c] * g[c] + b[c];
    x = x / (1.f + expf(-x));
    float skip = (float)qkvs[(size_t)n * 1664 + 1536 + c];
    h16[idx] = (_Float16)(x + skip);
}

// ---------------- output head + batch correction ----------------
__global__ void head_kernel(const float* __restrict__ feat, const float* __restrict__ fcow,
                            const float* __restrict__ fcob, const int* __restrict__ batch,
                            float* __restrict__ out, float* __restrict__ qa_buf,
                            float* __restrict__ qsum, float* __restrict__ cnt)
{
    int n = blockIdx.x * 256 + threadIdx.x;
    float ea = fcob[0], qa = fcob[1];
    for (int j = 0; j < DD; ++j) {
        float f = feat[(size_t)n * DD + j];
        ea += f * fcow[2 * j];
        qa += f * fcow[2 * j + 1];
    }
    out[2 * n] = ea;
    qa_buf[n] = qa;
    int b = batch[n];
    atomicAdd(&qsum[b], qa);
    atomicAdd(&cnt[b], 1.0f);
}

__global__ void final_kernel(const float* __restrict__ qa_buf, const int* __restrict__ batch,
                             const float* __restrict__ qsum, const float* __restrict__ cnt,
                             float* __restrict__ out)
{
    int n = blockIdx.x * 256 + threadIdx.x;
    int b = batch[n];
    out[2 * n + 1] = qa_buf[n] - qsum[b] / cnt[b];
}

// ---------------- launcher ----------------
extern "C" void kernel_launch(void* const* d_in, const int* in_sizes, int n_in,
                              void* d_out, int out_size, void* d_ws, size_t ws_size,
                              hipStream_t stream)
{
    const float* x         = (const float*)d_in[0];
    const float* edge_attr = (const float*)d_in[1];
    const int*   edge_index= (const int*)d_in[2];
    const int*   batch     = (const int*)d_in[3];
    const float* rbf_b1 = (const float*)d_in[7];
    const float* rbf_b2 = (const float*)d_in[9];
    const float* bcat = (const float*)d_in[18];
    const float* bm = (const float*)d_in[20];
    const float* lag = (const float*)d_in[21];
    const float* lab = (const float*)d_in[22];
    const float* bmsg = (const float*)d_in[24];
    const float* lmg = (const float*)d_in[25];
    const float* lmb = (const float*)d_in[26];
    const float* bn_g = (const float*)d_in[27];
    const float* bn_b = (const float*)d_in[28];
    const float* fc_b = (const float*)d_in[32];
    const float* fco_w = (const float*)d_in[33];
    const float* fco_b = (const float*)d_in[34];

    const int* src = edge_index;
    const int* dst = edge_index + NE;

    char* base = (char*)d_ws;
    size_t off = 0;
    auto alloc = [&](size_t bytes) -> char* {
        char* p = base + off;
        off += (bytes + 255) & ~(size_t)255;
        return p;
    };
    _Float16* wbuf   = (_Float16*)alloc((size_t)TOT_H * 2);
    float*    biasb  = (float*)alloc((size_t)5 * 1664 * 4);
    _Float16* x16    = (_Float16*)alloc((size_t)N_NODES * 96 * 2);
    _Float16* h16    = (_Float16*)alloc((size_t)N_NODES * DD * 2);
    _Float16* rbf16  = (_Float16*)alloc((size_t)NE * DD * 2);
    _Float16* tmp16  = (_Float16*)alloc((size_t)NE * DD * 2);
    _Float16* ef16   = (_Float16*)alloc((size_t)NE * DD * 2);
    _Float16* qkvs16 = (_Float16*)alloc((size_t)N_NODES * 1664 * 2);
    _Float16* ebuf16 = (_Float16*)alloc((size_t)NE * HC_ * 2);
    _Float16* p12    = (_Float16*)alloc((size_t)8192 * 768 * 2);
    float* agg    = (float*)alloc((size_t)N_NODES * HC_ * 4);
    float* outb   = (float*)alloc((size_t)N_NODES * CC_ * 4);
    float* featb  = (float*)alloc((size_t)N_NODES * DD * 4);
    float* qa_buf = (float*)alloc((size_t)N_NODES * 4);
    float* mu     = (float*)alloc(CC_ * 4);
    float* rv     = (float*)alloc(CC_ * 4);
    float* qsum   = (float*)alloc((size_t)NB * 2 * 4);
    float* cnt    = qsum + NB;

    // ---- weight prep (all layers) + input packs ----
    wprep_kernel<<<(TOT_ALL + 255) / 256, 256, 0, stream>>>(
        (const float*)d_in[10], (const float*)d_in[11], (const float*)d_in[12], (const float*)d_in[13],
        (const float*)d_in[14], (const float*)d_in[15], (const float*)d_in[29], (const float*)d_in[30],
        (const float*)d_in[19], (const float*)d_in[23], (const float*)d_in[16], (const float*)d_in[17],
        (const float*)d_in[4], (const float*)d_in[6], (const float*)d_in[8], (const float*)d_in[31],
        wbuf, biasb);
    xpack_kernel<<<(N_NODES * 96 + 255) / 256, 256, 0, stream>>>(x, x16);
    rbf_kernel<<<(NE * 128) / 256, 256, 0, stream>>>(edge_attr, rbf16);

    // h = x @ emb + emb_b  (K=96 zero-padded)
    gemm16<0, 0, false, false><<<dim3(16, 1), 256, 0, stream>>>(
        x16, 96, wbuf + OFF_EMBT, 96, 0, (const float*)d_in[5], h16, DD, 96);
    // ef = softplus(rbf@w1+b1) @ w2 + b2
    gemm16<0, 1, false, false><<<dim3(NE / 128, 1), 256, 0, stream>>>(
        rbf16, 128, wbuf + OFF_W1T, 128, 0, rbf_b1, tmp16, 128, 128);
    gemm16<0, 0, false, false><<<dim3(NE / 128, 1), 256, 0, stream>>>(
        tmp16, 128, wbuf + OFF_W2T, 128, 0, rbf_b2, ef16, 128, 128);

    for (int l = 0; l < NL; ++l) {
        const _Float16* lw = wbuf + (size_t)l * LWH;
        const float* bias_l = biasb + (size_t)l * 1664;
        const float* bcat_l = bcat + (size_t)l * CC_;
        const float* bm_l = bm + (size_t)l * C3_;
        const float* lag_l = lag + (size_t)l * C3_;
        const float* lab_l = lab + (size_t)l * C3_;
        const float* bmsg_l = bmsg + (size_t)l * CC_;
        const float* lmg_l = lmg + (size_t)l * CC_;
        const float* lmb_l = lmb + (size_t)l * CC_;
        const float* bng_l = bn_g + (size_t)l * CC_;
        const float* bnb_l = bn_b + (size_t)l * CC_;

        // qkvs = h @ [wq|wk|wv|wskip] + [bq|bk|bv|bskip]
        gemm16<0, 0, false, false><<<dim3(16, 13), 256, 0, stream>>>(
            h16, DD, lw + OFF_QKVST, 128, 0, bias_l, qkvs16, 1664, 128);
        // e = ef @ we
        gemm16<0, 0, false, false><<<dim3(NE / 128, 4), 256, 0, stream>>>(
            ef16, 128, lw + OFF_WET, 128, 0, nullptr, ebuf16, HC_, 128);
        // P1|P2 = v @ [wm_top | wm_mid]
        gemm16<2, 0, false, false><<<dim3(64, 6), 256, 0, stream>>>(
            qkvs16 + 1024, 1664, lw + OFF_W12T, 128, 0, nullptr, p12, 768, 128);

        // fused: P3 + gate + GEMM2 + row-LN + segment scatter
        hipMemsetAsync(agg, 0, (size_t)N_NODES * HC_ * sizeof(float), stream);
        fused_edge_kernel<<<NE / EB2, 256, 0, stream>>>(
            qkvs16, ebuf16, p12, lw + OFF_WM3T, lw + OFF_WMSGT,
            bm_l, lag_l, lab_l, bmsg_l, lmg_l, lmb_l, src, dst, agg);

        // outb = agg @ wcat + bcat (split-K), BN, silu, +skip -> h16
        hipMemsetAsync(outb, 0, (size_t)N_NODES * CC_ * sizeof(float), stream);
        gemm16<1, 0, false, true><<<dim3(16, 1, 4), 256, 0, stream>>>(
            agg, HC_, lw + OFF_WCATT, 512, 0, bcat_l, outb, CC_, 512);
        bn_stats_kernel<<<CC_, 256, 0, stream>>>(outb, mu, rv);
        bn_apply_kernel<<<(N_NODES * CC_) / 256, 256, 0, stream>>>(
            outb, qkvs16, mu, rv, bng_l, bnb_l, h16);
    }

    // feat = silu(h @ fc_w + fc_b)
    gemm16<0, 2, true, false><<<dim3(16, 1), 256, 0, stream>>>(
        h16, DD, wbuf + OFF_FCT, 128, 0, fc_b, featb, DD, 128);

    hipMemsetAsync(qsum, 0, (size_t)NB * 2 * sizeof(float), stream);
    head_kernel<<<N_NODES / 256, 256, 0, stream>>>(featb, fco_w, fco_b, batch,
                                                   (float*)d_out, qa_buf, qsum, cnt);
    final_kernel<<<N_NODES / 256, 256, 0, stream>>>(qa_buf, batch, qsum, cnt, (float*)d_out);
}

// Round 9
// 1070.816 us; speedup vs baseline: 1.6221x; 1.0641x over previous
//
#include <hip/hip_runtime.h>
#include <math.h>

#define N_NODES 2048
#define NE      16384
#define NB      64
#define FIN     92
#define DD      128
#define HH_     4
#define CC_     128
#define HC_     512
#define C3_     384
#define NL      5
#define EPSV    1e-5f

// per-layer packed fp16 weight block offsets (halves)
#define LWH        540672
#define OFF_QKVST  0        // [1664][128]
#define OFF_W12T   212992   // [768][128]
#define OFF_WM3T   311296   // [384][128]
#define OFF_WMSGT  360448   // [128][384]
#define OFF_WET    409600   // [512][128]
#define OFF_WCATT  475136   // [128][512]
#define EX0        (5*LWH)
#define OFF_EMBT   (EX0)            // [128][96]
#define OFF_W1T    (EX0+12288)      // [128][128]
#define OFF_W2T    (EX0+28672)      // [128][128]
#define OFF_FCT    (EX0+45056)      // [128][128]
#define TOT_H      (EX0+61440)
#define TOT_ALL    (TOT_H + 5*1664)

struct alignas(16) F4 { float v[4]; };
typedef _Float16 f16x8 __attribute__((ext_vector_type(8)));
typedef float f32x4 __attribute__((ext_vector_type(4)));
union H8 { f16x8 h; uint4 u; };

// ---------------- weight prep: transpose + fp16 convert, all layers ----------------
__global__ void wprep_kernel(const float* __restrict__ wq, const float* __restrict__ bq,
                             const float* __restrict__ wk, const float* __restrict__ bk,
                             const float* __restrict__ wv, const float* __restrict__ bv,
                             const float* __restrict__ wskip, const float* __restrict__ bskip,
                             const float* __restrict__ wm, const float* __restrict__ wmsg,
                             const float* __restrict__ we, const float* __restrict__ wcat,
                             const float* __restrict__ emb_w, const float* __restrict__ rbf_w1,
                             const float* __restrict__ rbf_w2, const float* __restrict__ fc_w,
                             _Float16* __restrict__ wb, float* __restrict__ bb)
{
    int idx = blockIdx.x * 256 + threadIdx.x;
    if (idx < 5 * LWH) {
        int l = idx / LWH, r = idx % LWH;
        float val;
        if (r < 212992) {
            int n = r >> 7, kk = r & 127;
            if (n < 512)       val = wq[(size_t)l * 65536 + kk * 512 + n];
            else if (n < 1024) val = wk[(size_t)l * 65536 + kk * 512 + (n - 512)];
            else if (n < 1536) val = wv[(size_t)l * 65536 + kk * 512 + (n - 1024)];
            else               val = wskip[(size_t)l * 16384 + kk * 128 + (n - 1536)];
        } else if (r < 311296) {
            int t = r - 212992; int n = t >> 7, kk = t & 127;
            val = (n < 384) ? wm[(size_t)l * 147456 + kk * 384 + n]
                            : wm[(size_t)l * 147456 + (128 + kk) * 384 + (n - 384)];
        } else if (r < 360448) {
            int t = r - 311296; int n = t >> 7, kk = t & 127;
            val = wm[(size_t)l * 147456 + (256 + kk) * 384 + n];
        } else if (r < 409600) {
            int t = r - 360448; int n = t / 384, kk = t % 384;
            val = wmsg[(size_t)l * 49152 + kk * 128 + n];
        } else if (r < 475136) {
            int t = r - 409600; int n = t >> 7, kk = t & 127;
            val = we[(size_t)l * 65536 + kk * 512 + n];
        } else {
            int t = r - 475136; int n = t >> 9, kk = t & 511;
            val = wcat[(size_t)l * 65536 + kk * 128 + n];
        }
        wb[idx] = (_Float16)val;
    } else if (idx < TOT_H) {
        int t = idx - EX0;
        float val;
        if (t < 12288)      { int n = t / 96, kk = t % 96; val = (kk < FIN) ? emb_w[kk * 128 + n] : 0.f; }
        else if (t < 28672) { int t2 = t - 12288; int n = t2 >> 7, kk = t2 & 127; val = rbf_w1[kk * 128 + n]; }
        else if (t < 45056) { int t2 = t - 28672; int n = t2 >> 7, kk = t2 & 127; val = rbf_w2[kk * 128 + n]; }
        else                { int t2 = t - 45056; int n = t2 >> 7, kk = t2 & 127; val = fc_w[kk * 128 + n]; }
        wb[idx] = (_Float16)val;
    } else if (idx < TOT_ALL) {
        int t = idx - TOT_H;
        int l = t / 1664, n = t % 1664;
        float val;
        if (n < 512)       val = bq[l * 512 + n];
        else if (n < 1024) val = bk[l * 512 + n - 512];
        else if (n < 1536) val = bv[l * 512 + n - 1024];
        else               val = bskip[l * 128 + n - 1536];
        bb[t] = val;
    }
}

// ---------------- x -> fp16 padded to 96 ----------------
__global__ void xpack_kernel(const float* __restrict__ x, _Float16* __restrict__ x16)
{
    int idx = blockIdx.x * 256 + threadIdx.x;
    if (idx >= N_NODES * 96) return;
    int n = idx / 96, kk = idx % 96;
    x16[idx] = (kk < FIN) ? (_Float16)x[n * FIN + kk] : (_Float16)0.f;
}

// ---------------- RBF expansion (fp16 out) ----------------
__global__ void rbf_kernel(const float* __restrict__ eattr, _Float16* __restrict__ rbf)
{
    int idx = blockIdx.x * 256 + threadIdx.x;
    int e = idx >> 7, c = idx & 127;
    float x0 = eattr[e * 3 + 0], x1 = eattr[e * 3 + 1], x2 = eattr[e * 3 + 2];
    float d = sqrtf(x0 * x0 + x1 * x1 + x2 * x2);
    float ctr = (8.0f / 127.0f) * (float)c;
    float t = d - ctr;
    rbf[idx] = (_Float16)expf(-15.875f * t * t);
}

// ---------------- unified fp16 MFMA GEMM ----------------
template<int AMODE, int ACT, bool OUT_F32, bool SPLITK>
__global__ __launch_bounds__(256) void gemm16(
    const void* __restrict__ Av, int lda,
    const _Float16* __restrict__ Bt, int ldb, int bkoff,
    const float* __restrict__ bias,
    void* __restrict__ Cv, int ldc, int K)
{
    __shared__ alignas(16) _Float16 As[128 * 40];
    __shared__ alignas(16) _Float16 Bs[128 * 40];
    const int tid = threadIdx.x;
    const int w = tid >> 6, l = tid & 63;
    const int g = l >> 4, c = l & 15;
    const int row0 = blockIdx.x * 128;
    const int col0 = blockIdx.y * 128;
    int k0 = 0, kend = K;
    if (SPLITK) { int ks = K / gridDim.z; k0 = blockIdx.z * ks; kend = k0 + ks; }
    f32x4 acc[2][8] = {};
    for (int kb = k0; kb < kend; kb += 32) {
        __syncthreads();
        #pragma unroll
        for (int i = 0; i < 2; ++i) {
            int p = tid + 256 * i;
            int r = p >> 2, q = p & 3;
            *(uint4*)&Bs[r * 40 + q * 8] =
                *(const uint4*)&Bt[(size_t)(col0 + r) * ldb + bkoff + kb + q * 8];
            if (AMODE == 1) {
                const float* Af = (const float*)Av;
                const float* ap = Af + (size_t)(row0 + r) * lda + kb + q * 8;
                F4 x0 = *(const F4*)ap;
                F4 x1 = *(const F4*)(ap + 4);
                union { _Float16 h[8]; uint4 u; } cv;
                #pragma unroll
                for (int j = 0; j < 4; ++j) { cv.h[j] = (_Float16)x0.v[j]; cv.h[4 + j] = (_Float16)x1.v[j]; }
                *(uint4*)&As[r * 40 + q * 8] = cv.u;
            } else if (AMODE == 2) {
                const _Float16* Ah = (const _Float16*)Av;
                int row = row0 + r;
                *(uint4*)&As[r * 40 + q * 8] =
                    *(const uint4*)&Ah[(size_t)(row >> 2) * lda + (row & 3) * 128 + kb + q * 8];
            } else {
                const _Float16* Ah = (const _Float16*)Av;
                *(uint4*)&As[r * 40 + q * 8] =
                    *(const uint4*)&Ah[(size_t)(row0 + r) * lda + kb + q * 8];
            }
        }
        __syncthreads();
        f16x8 af[2], bf[8];
        #pragma unroll
        for (int mi = 0; mi < 2; ++mi)
            af[mi] = *(const f16x8*)&As[(w * 32 + mi * 16 + c) * 40 + g * 8];
        #pragma unroll
        for (int ni = 0; ni < 8; ++ni)
            bf[ni] = *(const f16x8*)&Bs[(ni * 16 + c) * 40 + g * 8];
        #pragma unroll
        for (int mi = 0; mi < 2; ++mi)
            #pragma unroll
            for (int ni = 0; ni < 8; ++ni)
                acc[mi][ni] = __builtin_amdgcn_mfma_f32_16x16x32_f16(af[mi], bf[ni], acc[mi][ni], 0, 0, 0);
    }
    const bool addb = bias && (!SPLITK || blockIdx.z == 0);
    #pragma unroll
    for (int mi = 0; mi < 2; ++mi)
        #pragma unroll
        for (int ni = 0; ni < 8; ++ni)
            #pragma unroll
            for (int i = 0; i < 4; ++i) {
                int row = row0 + w * 32 + mi * 16 + g * 4 + i;
                int col = col0 + ni * 16 + c;
                float v = acc[mi][ni][i] + (addb ? bias[col] : 0.f);
                if (ACT == 1) v = fmaxf(v, 0.f) + log1pf(expf(-fabsf(v)));
                else if (ACT == 2) v = v / (1.f + expf(-v));
                if (SPLITK)       atomicAdd((float*)Cv + (size_t)row * ldc + col, v);
                else if (OUT_F32) ((float*)Cv)[(size_t)row * ldc + col] = v;
                else              ((_Float16*)Cv)[(size_t)row * ldc + col] = (_Float16)v;
            }
}

// ---------------- fused edge kernel v4: rolled loop, slim LDS, global q/k in t-build ----
// Per block: 16 edges = 64 edge-head rows, 4 waves. Stats phase parallel (v1 style);
// gate recomputed per chunk from f32 alpha with __expf; chunk loop NOT unrolled.
#define EB2 16
#define RW2 64

__global__ __launch_bounds__(256, 4) void fused_edge_kernel(
    const _Float16* __restrict__ qkvs,   // [2048][1664]
    const _Float16* __restrict__ e16,    // [65536][128]
    const _Float16* __restrict__ p12,    // [8192][768]
    const _Float16* __restrict__ wm3T,   // [384][128]
    const _Float16* __restrict__ wmsgT,  // [128][384]
    const float* __restrict__ bm, const float* __restrict__ lag, const float* __restrict__ lab,
    const float* __restrict__ bmsg, const float* __restrict__ lmg, const float* __restrict__ lmb,
    const int* __restrict__ src, const int* __restrict__ dst,
    float* __restrict__ agg)
{
    __shared__ alignas(16) _Float16 St [RW2 * 40];   // p3 chunk -> t chunk; also f32 stats scratch
    __shared__ alignas(16) _Float16 Bs3[32 * 136];
    __shared__ alignas(16) _Float16 Bsg[128 * 40];
    __shared__ float2 murs[RW2];
    __shared__ int dstn[EB2], srcn[EB2];

    const int tid = threadIdx.x;
    const int w = tid >> 6, l = tid & 63;
    const int g = l >> 4, c = l & 15;
    const int e0 = blockIdx.x * EB2;
    const int row0 = blockIdx.x * RW2;
    const float ISQ = 0.05103103630798287f;  // 1/sqrt(384)

    if (tid < EB2) { dstn[tid] = dst[e0 + tid]; srcn[tid] = src[e0 + tid]; }

    // P3 A-fragments: e rows contiguous; reused for every chunk. (row = row0+w*16+c)
    f16x8 af3[4];
    {
        const _Float16* ep = e16 + (size_t)(row0 + w * 16 + c) * 128;
        #pragma unroll
        for (int ks = 0; ks < 4; ++ks) af3[ks] = *(const f16x8*)(ep + ks * 32 + g * 8);
    }
    __syncthreads();

    // ---- phase 1: parallel alpha LN stats (no LDS staging of q/k/e) ----
    {
        int r = tid & 63, piece = tid >> 6;
        int el = r >> 2, hh = r & 3;
        int ni = dstn[el], nj = srcn[el];
        const _Float16* qp  = qkvs + (size_t)ni * 1664 + hh * 128 + piece * 32;
        const _Float16* kip = qkvs + (size_t)ni * 1664 + 512 + hh * 128 + piece * 32;
        const _Float16* kjp = qkvs + (size_t)nj * 1664 + 512 + hh * 128 + piece * 32;
        const _Float16* ep  = e16 + (size_t)(row0 + r) * 128 + piece * 32;
        float s1 = 0.f, s2 = 0.f;
        #pragma unroll
        for (int v = 0; v < 4; ++v) {
            f16x8 qv  = *(const f16x8*)(qp + v * 8);
            f16x8 kiv = *(const f16x8*)(kip + v * 8);
            f16x8 kjv = *(const f16x8*)(kjp + v * 8);
            f16x8 ev  = *(const f16x8*)(ep + v * 8);
            #pragma unroll
            for (int j = 0; j < 8; ++j) {
                float q = (float)qv[j];
                float a0 = q * (float)kiv[j] * ISQ;
                float a1 = q * (float)kjv[j] * ISQ;
                float a2 = q * (float)ev[j] * ISQ;
                s1 += a0 + a1 + a2;
                s2 += a0 * a0 + a1 * a1 + a2 * a2;
            }
        }
        ((float2*)St)[piece * 64 + r] = make_float2(s1, s2);
    }
    __syncthreads();
    if (tid < 64) {
        float2* red = (float2*)St;
        float S1 = 0.f, S2 = 0.f;
        #pragma unroll
        for (int p = 0; p < 4; ++p) { float2 v = red[p * 64 + tid]; S1 += v.x; S2 += v.y; }
        float mu = S1 * (1.f / 384.f);
        float var = S2 * (1.f / 384.f) - mu * mu;
        murs[tid] = make_float2(mu, rsqrtf(var + EPSV));
    }

    // per-thread t-build pointers (thread owns row r_own = tid>>2, cols cp*8 per chunk)
    const int r_own = tid >> 2, cp = tid & 3;
    const int edge_o = r_own >> 2, hh_o = r_own & 3;
    __syncthreads();
    const int nd_o = dstn[edge_o], ns_o = srcn[edge_o];
    const _Float16* qpo  = qkvs + (size_t)nd_o * 1664 + hh_o * 128;
    const _Float16* kipo = qkvs + (size_t)nd_o * 1664 + 512 + hh_o * 128;
    const _Float16* kjpo = qkvs + (size_t)ns_o * 1664 + 512 + hh_o * 128;
    const _Float16* epo  = e16 + (size_t)(row0 + r_own) * 128;
    const _Float16* p1p  = p12 + ((size_t)nd_o * 4 + hh_o) * 768;
    const _Float16* p2p  = p12 + ((size_t)ns_o * 4 + hh_o) * 768 + 384;

    // ---- chunk loop over K=384 in 32-col chunks (ROLLED - keep body icache-resident) ----
    f32x4 acc2[8] = {};
    #pragma unroll 1
    for (int ck = 0; ck < 12; ++ck) {
        __syncthreads();   // prior GEMM2 done reading Bsg/St
        // stage B panels (L2-hot weights)
        #pragma unroll
        for (int i = 0; i < 2; ++i) {
            int p = tid + 256 * i;
            int col = p >> 4, q8 = p & 15;
            *(f16x8*)&Bs3[col * 136 + q8 * 8] =
                *(const f16x8*)&wm3T[(size_t)(ck * 32 + col) * 128 + q8 * 8];
        }
        #pragma unroll
        for (int i = 0; i < 2; ++i) {
            int p = tid + 256 * i;
            int col = p >> 2, q4i = p & 3;
            *(f16x8*)&Bsg[col * 40 + q4i * 8] =
                *(const f16x8*)&wmsgT[(size_t)col * 384 + ck * 32 + q4i * 8];
        }
        __syncthreads();

        // P3 chunk: wave w -> rows w*16.., 32 cols
        f32x4 a3[2] = {};
        #pragma unroll
        for (int ks = 0; ks < 4; ++ks)
            #pragma unroll
            for (int nt = 0; nt < 2; ++nt) {
                f16x8 bf = *(const f16x8*)&Bs3[(nt * 16 + c) * 136 + ks * 32 + g * 8];
                a3[nt] = __builtin_amdgcn_mfma_f32_16x16x32_f16(af3[ks], bf, a3[nt], 0, 0, 0);
            }
        #pragma unroll
        for (int nt = 0; nt < 2; ++nt)
            #pragma unroll
            for (int i = 0; i < 4; ++i)
                St[(w * 16 + g * 4 + i) * 40 + nt * 16 + c] = (_Float16)a3[nt][i];
        __syncthreads();

        // t-build in place: gate recomputed from f32 alpha (q/sel from L2-hot global)
        {
            int kk0 = ck * 32 + cp * 8;
            int s = kk0 >> 7, cc0 = kk0 & 127;
            const _Float16* selp = (s == 0) ? kipo : (s == 1) ? kjpo : epo;
            f16x8 qv = *(const f16x8*)(qpo + cc0);
            f16x8 sv = *(const f16x8*)(selp + cc0);
            f16x8 p1v = *(const f16x8*)(p1p + kk0);
            f16x8 p2v = *(const f16x8*)(p2p + kk0);
            f16x8 p3v = *(const f16x8*)&St[r_own * 40 + cp * 8];
            F4 lg0 = *(const F4*)(lag + kk0), lg1 = *(const F4*)(lag + kk0 + 4);
            F4 lb0 = *(const F4*)(lab + kk0), lb1 = *(const F4*)(lab + kk0 + 4);
            F4 bm0 = *(const F4*)(bm + kk0),  bm1 = *(const F4*)(bm + kk0 + 4);
            float2 mr = murs[r_own];
            H8 tv;
            #pragma unroll
            for (int j = 0; j < 8; ++j) {
                float lgv = (j < 4) ? lg0.v[j] : lg1.v[j - 4];
                float lbv = (j < 4) ? lb0.v[j] : lb1.v[j - 4];
                float bmv = (j < 4) ? bm0.v[j] : bm1.v[j - 4];
                float a = (float)qv[j] * (float)sv[j] * ISQ;
                float z = (a - mr.x) * mr.y * lgv + lbv;
                float gate = 1.f / (1.f + __expf(-z));
                float t = (float)p1v[j] + (float)p2v[j] + (float)p3v[j] + bmv;
                tv.h[j] = (_Float16)(t * gate);
            }
            *(f16x8*)&St[r_own * 40 + cp * 8] = tv.h;
        }
        __syncthreads();

        // GEMM2 accumulate: wave w -> rows w*16.., all 8 n-tiles
        {
            f16x8 af2 = *(const f16x8*)&St[(w * 16 + c) * 40 + g * 8];
            #pragma unroll
            for (int ni = 0; ni < 8; ++ni) {
                f16x8 bf = *(const f16x8*)&Bsg[(ni * 16 + c) * 40 + g * 8];
                acc2[ni] = __builtin_amdgcn_mfma_f32_16x16x32_f16(af2, bf, acc2[ni], 0, 0, 0);
            }
        }
    }

    // ---- epilogue: +bmsg, row-LN(128), scatter-add (rows w*16 + g*4 + i) ----
    float bz[8], lgv2[8], lbv2[8];
    #pragma unroll
    for (int ni = 0; ni < 8; ++ni) {
        int colc = ni * 16 + c;
        bz[ni] = bmsg[colc]; lgv2[ni] = lmg[colc]; lbv2[ni] = lmb[colc];
    }
    #pragma unroll
    for (int i = 0; i < 4; ++i) {
        float u[8];
        float s1 = 0.f, s2 = 0.f;
        #pragma unroll
        for (int ni = 0; ni < 8; ++ni) {
            u[ni] = acc2[ni][i] + bz[ni];
            s1 += u[ni]; s2 += u[ni] * u[ni];
        }
        #pragma unroll
        for (int off = 1; off < 16; off <<= 1) {
            s1 += __shfl_xor(s1, off);
            s2 += __shfl_xor(s2, off);
        }
        float mu = s1 * (1.f / 128.f);
        float var = s2 * (1.f / 128.f) - mu * mu;
        float rs = rsqrtf(var + EPSV);
        int r = w * 16 + g * 4 + i;
        int el = r >> 2, hh = r & 3;
        int nd = dstn[el];
        float* ap = agg + (size_t)nd * HC_ + hh * CC_;
        #pragma unroll
        for (int ni = 0; ni < 8; ++ni) {
            float msg = (u[ni] - mu) * rs * lgv2[ni] + lbv2[ni];
            atomicAdd(ap + ni * 16 + c, msg);
        }
    }
}

// ---------------- BN stats over nodes (per channel) ----------------
__global__ void bn_stats_kernel(const float* __restrict__ outb,
                                float* __restrict__ mu, float* __restrict__ rv)
{
    int c = blockIdx.x;
    int tid = threadIdx.x;
    float s = 0.f, s2 = 0.f;
    for (int r = tid; r < N_NODES; r += 256) {
        float x = outb[(size_t)r * CC_ + c];
        s += x; s2 += x * x;
    }
    #pragma unroll
    for (int off = 1; off < 64; off <<= 1) {
        s += __shfl_xor(s, off);
        s2 += __shfl_xor(s2, off);
    }
    __shared__ float ls[8];
    int w = tid >> 6, ln = tid & 63;
    if (ln == 0) { ls[w] = s; ls[4 + w] = s2; }
    __syncthreads();
    if (tid == 0) {
        float S = ls[0] + ls[1] + ls[2] + ls[3];
        float S2 = ls[4] + ls[5] + ls[6] + ls[7];
        float m = S * (1.f / N_NODES);
        float var = S2 * (1.f / N_NODES) - m * m;
        mu[c] = m;
        rv[c] = rsqrtf(var + EPSV);
    }
}

// ---------------- BN apply + silu + residual(skip) -> h16 ----------------
__global__ void bn_apply_kernel(const float* __restrict__ outb, const _Float16* __restrict__ qkvs,
                                const float* __restrict__ mu, const float* __restrict__ rv,
                                const float* __restrict__ g, const float* __restrict__ b,
                                _Float16* __restrict__ h16)
{
    int idx = blockIdx.x * 256 + threadIdx.x;
    int n = idx >> 7, c = idx & (CC_ - 1);
    float x = (outb[idx] - mu[c]) * rv[c] * g[c] + b[c];
    x = x / (1.f + expf(-x));
    float skip = (float)qkvs[(size_t)n * 1664 + 1536 + c];
    h16[idx] = (_Float16)(x + skip);
}

// ---------------- output head + batch correction ----------------
__global__ void head_kernel(const float* __restrict__ feat, const float* __restrict__ fcow,
                            const float* __restrict__ fcob, const int* __restrict__ batch,
                            float* __restrict__ out, float* __restrict__ qa_buf,
                            float* __restrict__ qsum, float* __restrict__ cnt)
{
    int n = blockIdx.x * 256 + threadIdx.x;
    float ea = fcob[0], qa = fcob[1];
    for (int j = 0; j < DD; ++j) {
        float f = feat[(size_t)n * DD + j];
        ea += f * fcow[2 * j];
        qa += f * fcow[2 * j + 1];
    }
    out[2 * n] = ea;
    qa_buf[n] = qa;
    int b = batch[n];
    atomicAdd(&qsum[b], qa);
    atomicAdd(&cnt[b], 1.0f);
}

__global__ void final_kernel(const float* __restrict__ qa_buf, const int* __restrict__ batch,
                             const float* __restrict__ qsum, const float* __restrict__ cnt,
                             float* __restrict__ out)
{
    int n = blockIdx.x * 256 + threadIdx.x;
    int b = batch[n];
    out[2 * n + 1] = qa_buf[n] - qsum[b] / cnt[b];
}

// ---------------- launcher ----------------
extern "C" void kernel_launch(void* const* d_in, const int* in_sizes, int n_in,
                              void* d_out, int out_size, void* d_ws, size_t ws_size,
                              hipStream_t stream)
{
    const float* x         = (const float*)d_in[0];
    const float* edge_attr = (const float*)d_in[1];
    const int*   edge_index= (const int*)d_in[2];
    const int*   batch     = (const int*)d_in[3];
    const float* rbf_b1 = (const float*)d_in[7];
    const float* rbf_b2 = (const float*)d_in[9];
    const float* bcat = (const float*)d_in[18];
    const float* bm = (const float*)d_in[20];
    const float* lag = (const float*)d_in[21];
    const float* lab = (const float*)d_in[22];
    const float* bmsg = (const float*)d_in[24];
    const float* lmg = (const float*)d_in[25];
    const float* lmb = (const float*)d_in[26];
    const float* bn_g = (const float*)d_in[27];
    const float* bn_b = (const float*)d_in[28];
    const float* fc_b = (const float*)d_in[32];
    const float* fco_w = (const float*)d_in[33];
    const float* fco_b = (const float*)d_in[34];

    const int* src = edge_index;
    const int* dst = edge_index + NE;

    char* base = (char*)d_ws;
    size_t off = 0;
    auto alloc = [&](size_t bytes) -> char* {
        char* p = base + off;
        off += (bytes + 255) & ~(size_t)255;
        return p;
    };
    _Float16* wbuf   = (_Float16*)alloc((size_t)TOT_H * 2);
    float*    biasb  = (float*)alloc((size_t)5 * 1664 * 4);
    _Float16* x16    = (_Float16*)alloc((size_t)N_NODES * 96 * 2);
    _Float16* h16    = (_Float16*)alloc((size_t)N_NODES * DD * 2);
    _Float16* rbf16  = (_Float16*)alloc((size_t)NE * DD * 2);
    _Float16* tmp16  = (_Float16*)alloc((size_t)NE * DD * 2);
    _Float16* ef16   = (_Float16*)alloc((size_t)NE * DD * 2);
    _Float16* qkvs16 = (_Float16*)alloc((size_t)N_NODES * 1664 * 2);
    _Float16* ebuf16 = (_Float16*)alloc((size_t)NE * HC_ * 2);
    _Float16* p12    = (_Float16*)alloc((size_t)8192 * 768 * 2);
    float* agg    = (float*)alloc((size_t)N_NODES * HC_ * 4);
    float* outb   = (float*)alloc((size_t)N_NODES * CC_ * 4);   // contiguous after agg
    float* featb  = (float*)alloc((size_t)N_NODES * DD * 4);
    float* qa_buf = (float*)alloc((size_t)N_NODES * 4);
    float* mu     = (float*)alloc(CC_ * 4);
    float* rv     = (float*)alloc(CC_ * 4);
    float* qsum   = (float*)alloc((size_t)NB * 2 * 4);
    float* cnt    = qsum + NB;

    // ---- weight prep (all layers) + input packs ----
    wprep_kernel<<<(TOT_ALL + 255) / 256, 256, 0, stream>>>(
        (const float*)d_in[10], (const float*)d_in[11], (const float*)d_in[12], (const float*)d_in[13],
        (const float*)d_in[14], (const float*)d_in[15], (const float*)d_in[29], (const float*)d_in[30],
        (const float*)d_in[19], (const float*)d_in[23], (const float*)d_in[16], (const float*)d_in[17],
        (const float*)d_in[4], (const float*)d_in[6], (const float*)d_in[8], (const float*)d_in[31],
        wbuf, biasb);
    xpack_kernel<<<(N_NODES * 96 + 255) / 256, 256, 0, stream>>>(x, x16);
    rbf_kernel<<<(NE * 128) / 256, 256, 0, stream>>>(edge_attr, rbf16);

    // h = x @ emb + emb_b  (K=96 zero-padded)
    gemm16<0, 0, false, false><<<dim3(16, 1), 256, 0, stream>>>(
        x16, 96, wbuf + OFF_EMBT, 96, 0, (const float*)d_in[5], h16, DD, 96);
    // ef = softplus(rbf@w1+b1) @ w2 + b2
    gemm16<0, 1, false, false><<<dim3(NE / 128, 1), 256, 0, stream>>>(
        rbf16, 128, wbuf + OFF_W1T, 128, 0, rbf_b1, tmp16, 128, 128);
    gemm16<0, 0, false, false><<<dim3(NE / 128, 1), 256, 0, stream>>>(
        tmp16, 128, wbuf + OFF_W2T, 128, 0, rbf_b2, ef16, 128, 128);

    for (int l = 0; l < NL; ++l) {
        const _Float16* lw = wbuf + (size_t)l * LWH;
        const float* bias_l = biasb + (size_t)l * 1664;
        const float* bcat_l = bcat + (size_t)l * CC_;
        const float* bm_l = bm + (size_t)l * C3_;
        const float* lag_l = lag + (size_t)l * C3_;
        const float* lab_l = lab + (size_t)l * C3_;
        const float* bmsg_l = bmsg + (size_t)l * CC_;
        const float* lmg_l = lmg + (size_t)l * CC_;
        const float* lmb_l = lmb + (size_t)l * CC_;
        const float* bng_l = bn_g + (size_t)l * CC_;
        const float* bnb_l = bn_b + (size_t)l * CC_;

        // qkvs = h @ [wq|wk|wv|wskip] + [bq|bk|bv|bskip]
        gemm16<0, 0, false, false><<<dim3(16, 13), 256, 0, stream>>>(
            h16, DD, lw + OFF_QKVST, 128, 0, bias_l, qkvs16, 1664, 128);
        // e = ef @ we
        gemm16<0, 0, false, false><<<dim3(NE / 128, 4), 256, 0, stream>>>(
            ef16, 128, lw + OFF_WET, 128, 0, nullptr, ebuf16, HC_, 128);
        // P1|P2 = v @ [wm_top | wm_mid]
        gemm16<2, 0, false, false><<<dim3(64, 6), 256, 0, stream>>>(
            qkvs16 + 1024, 1664, lw + OFF_W12T, 128, 0, nullptr, p12, 768, 128);

        // fused: P3 + gate + GEMM2 + row-LN + segment scatter
        hipMemsetAsync(agg, 0, ((size_t)N_NODES * HC_ + (size_t)N_NODES * CC_) * sizeof(float), stream);
        fused_edge_kernel<<<NE / EB2, 256, 0, stream>>>(
            qkvs16, ebuf16, p12, lw + OFF_WM3T, lw + OFF_WMSGT,
            bm_l, lag_l, lab_l, bmsg_l, lmg_l, lmb_l, src, dst, agg);

        // outb = agg @ wcat + bcat (split-K), BN, silu, +skip -> h16
        gemm16<1, 0, false, true><<<dim3(16, 1, 4), 256, 0, stream>>>(
            agg, HC_, lw + OFF_WCATT, 512, 0, bcat_l, outb, CC_, 512);
        bn_stats_kernel<<<CC_, 256, 0, stream>>>(outb, mu, rv);
        bn_apply_kernel<<<(N_NODES * CC_) / 256, 256, 0, stream>>>(
            outb, qkvs16, mu, rv, bng_l, bnb_l, h16);
    }

    // feat = silu(h @ fc_w + fc_b)
    gemm16<0, 2, true, false><<<dim3(16, 1), 256, 0, stream>>>(
        h16, DD, wbuf + OFF_FCT, 128, 0, fc_b, featb, DD, 128);

    hipMemsetAsync(qsum, 0, (size_t)NB * 2 * sizeof(float), stream);
    head_kernel<<<N_NODES / 256, 256, 0, stream>>>(featb, fco_w, fco_b, batch,
                                                   (float*)d_out, qa_buf, qsum, cnt);
    final_kernel<<<N_NODES / 256, 256, 0, stream>>>(qa_buf, batch, qsum, cnt, (float*)d_out);
}

// Round 10
// 1027.989 us; speedup vs baseline: 1.6896x; 1.0417x over previous
//
#include <hip/hip_runtime.h>
#include <math.h>

#define N_NODES 2048
#define NE      16384
#define NB      64
#define FIN     92
#define DD      128
#define HH_     4
#define CC_     128
#define HC_     512
#define C3_     384
#define NL      5
#define EPSV    1e-5f

// per-layer packed fp16 weight block offsets (halves)
#define LWH        540672
#define OFF_QKVST  0        // [1664][128]
#define OFF_W12T   212992   // [768][128]
#define OFF_WM3T   311296   // [384][128]
#define OFF_WMSGT  360448   // [128][384]
#define OFF_WET    409600   // [512][128]
#define OFF_WCATT  475136   // [128][512]
#define EX0        (5*LWH)
#define OFF_EMBT   (EX0)            // [128][96]
#define OFF_W1T    (EX0+12288)      // [128][128]
#define OFF_W2T    (EX0+28672)      // [128][128]
#define OFF_FCT    (EX0+45056)      // [128][128]
#define TOT_H      (EX0+61440)
#define TOT_ALL    (TOT_H + 5*1664)

struct alignas(16) F4 { float v[4]; };
typedef _Float16 f16x8 __attribute__((ext_vector_type(8)));
typedef float f32x4 __attribute__((ext_vector_type(4)));
union H8 { f16x8 h; uint4 u; };

// ---------------- weight prep: transpose + fp16 convert, all layers ----------------
__global__ void wprep_kernel(const float* __restrict__ wq, const float* __restrict__ bq,
                             const float* __restrict__ wk, const float* __restrict__ bk,
                             const float* __restrict__ wv, const float* __restrict__ bv,
                             const float* __restrict__ wskip, const float* __restrict__ bskip,
                             const float* __restrict__ wm, const float* __restrict__ wmsg,
                             const float* __restrict__ we, const float* __restrict__ wcat,
                             const float* __restrict__ emb_w, const float* __restrict__ rbf_w1,
                             const float* __restrict__ rbf_w2, const float* __restrict__ fc_w,
                             _Float16* __restrict__ wb, float* __restrict__ bb)
{
    int idx = blockIdx.x * 256 + threadIdx.x;
    if (idx < 5 * LWH) {
        int l = idx / LWH, r = idx % LWH;
        float val;
        if (r < 212992) {
            int n = r >> 7, kk = r & 127;
            if (n < 512)       val = wq[(size_t)l * 65536 + kk * 512 + n];
            else if (n < 1024) val = wk[(size_t)l * 65536 + kk * 512 + (n - 512)];
            else if (n < 1536) val = wv[(size_t)l * 65536 + kk * 512 + (n - 1024)];
            else               val = wskip[(size_t)l * 16384 + kk * 128 + (n - 1536)];
        } else if (r < 311296) {
            int t = r - 212992; int n = t >> 7, kk = t & 127;
            val = (n < 384) ? wm[(size_t)l * 147456 + kk * 384 + n]
                            : wm[(size_t)l * 147456 + (128 + kk) * 384 + (n - 384)];
        } else if (r < 360448) {
            int t = r - 311296; int n = t >> 7, kk = t & 127;
            val = wm[(size_t)l * 147456 + (256 + kk) * 384 + n];
        } else if (r < 409600) {
            int t = r - 360448; int n = t / 384, kk = t % 384;
            val = wmsg[(size_t)l * 49152 + kk * 128 + n];
        } else if (r < 475136) {
            int t = r - 409600; int n = t >> 7, kk = t & 127;
            val = we[(size_t)l * 65536 + kk * 512 + n];
        } else {
            int t = r - 475136; int n = t >> 9, kk = t & 511;
            val = wcat[(size_t)l * 65536 + kk * 128 + n];
        }
        wb[idx] = (_Float16)val;
    } else if (idx < TOT_H) {
        int t = idx - EX0;
        float val;
        if (t < 12288)      { int n = t / 96, kk = t % 96; val = (kk < FIN) ? emb_w[kk * 128 + n] : 0.f; }
        else if (t < 28672) { int t2 = t - 12288; int n = t2 >> 7, kk = t2 & 127; val = rbf_w1[kk * 128 + n]; }
        else if (t < 45056) { int t2 = t - 28672; int n = t2 >> 7, kk = t2 & 127; val = rbf_w2[kk * 128 + n]; }
        else                { int t2 = t - 45056; int n = t2 >> 7, kk = t2 & 127; val = fc_w[kk * 128 + n]; }
        wb[idx] = (_Float16)val;
    } else if (idx < TOT_ALL) {
        int t = idx - TOT_H;
        int l = t / 1664, n = t % 1664;
        float val;
        if (n < 512)       val = bq[l * 512 + n];
        else if (n < 1024) val = bk[l * 512 + n - 512];
        else if (n < 1536) val = bv[l * 512 + n - 1024];
        else               val = bskip[l * 128 + n - 1536];
        bb[t] = val;
    }
}

// ---------------- x -> fp16 padded to 96 ----------------
__global__ void xpack_kernel(const float* __restrict__ x, _Float16* __restrict__ x16)
{
    int idx = blockIdx.x * 256 + threadIdx.x;
    if (idx >= N_NODES * 96) return;
    int n = idx / 96, kk = idx % 96;
    x16[idx] = (kk < FIN) ? (_Float16)x[n * FIN + kk] : (_Float16)0.f;
}

// ---------------- RBF expansion (fp16 out) ----------------
__global__ void rbf_kernel(const float* __restrict__ eattr, _Float16* __restrict__ rbf)
{
    int idx = blockIdx.x * 256 + threadIdx.x;
    int e = idx >> 7, c = idx & 127;
    float x0 = eattr[e * 3 + 0], x1 = eattr[e * 3 + 1], x2 = eattr[e * 3 + 2];
    float d = sqrtf(x0 * x0 + x1 * x1 + x2 * x2);
    float ctr = (8.0f / 127.0f) * (float)c;
    float t = d - ctr;
    rbf[idx] = (_Float16)expf(-15.875f * t * t);
}

// ---------------- unified fp16 MFMA GEMM ----------------
template<int AMODE, int ACT, bool OUT_F32, bool SPLITK>
__global__ __launch_bounds__(256) void gemm16(
    const void* __restrict__ Av, int lda,
    const _Float16* __restrict__ Bt, int ldb, int bkoff,
    const float* __restrict__ bias,
    void* __restrict__ Cv, int ldc, int K)
{
    __shared__ alignas(16) _Float16 As[128 * 40];
    __shared__ alignas(16) _Float16 Bs[128 * 40];
    const int tid = threadIdx.x;
    const int w = tid >> 6, l = tid & 63;
    const int g = l >> 4, c = l & 15;
    const int row0 = blockIdx.x * 128;
    const int col0 = blockIdx.y * 128;
    int k0 = 0, kend = K;
    if (SPLITK) { int ks = K / gridDim.z; k0 = blockIdx.z * ks; kend = k0 + ks; }
    f32x4 acc[2][8] = {};
    for (int kb = k0; kb < kend; kb += 32) {
        __syncthreads();
        #pragma unroll
        for (int i = 0; i < 2; ++i) {
            int p = tid + 256 * i;
            int r = p >> 2, q = p & 3;
            *(uint4*)&Bs[r * 40 + q * 8] =
                *(const uint4*)&Bt[(size_t)(col0 + r) * ldb + bkoff + kb + q * 8];
            if (AMODE == 1) {
                const float* Af = (const float*)Av;
                const float* ap = Af + (size_t)(row0 + r) * lda + kb + q * 8;
                F4 x0 = *(const F4*)ap;
                F4 x1 = *(const F4*)(ap + 4);
                union { _Float16 h[8]; uint4 u; } cv;
                #pragma unroll
                for (int j = 0; j < 4; ++j) { cv.h[j] = (_Float16)x0.v[j]; cv.h[4 + j] = (_Float16)x1.v[j]; }
                *(uint4*)&As[r * 40 + q * 8] = cv.u;
            } else if (AMODE == 2) {
                const _Float16* Ah = (const _Float16*)Av;
                int row = row0 + r;
                *(uint4*)&As[r * 40 + q * 8] =
                    *(const uint4*)&Ah[(size_t)(row >> 2) * lda + (row & 3) * 128 + kb + q * 8];
            } else {
                const _Float16* Ah = (const _Float16*)Av;
                *(uint4*)&As[r * 40 + q * 8] =
                    *(const uint4*)&Ah[(size_t)(row0 + r) * lda + kb + q * 8];
            }
        }
        __syncthreads();
        f16x8 af[2], bf[8];
        #pragma unroll
        for (int mi = 0; mi < 2; ++mi)
            af[mi] = *(const f16x8*)&As[(w * 32 + mi * 16 + c) * 40 + g * 8];
        #pragma unroll
        for (int ni = 0; ni < 8; ++ni)
            bf[ni] = *(const f16x8*)&Bs[(ni * 16 + c) * 40 + g * 8];
        #pragma unroll
        for (int mi = 0; mi < 2; ++mi)
            #pragma unroll
            for (int ni = 0; ni < 8; ++ni)
                acc[mi][ni] = __builtin_amdgcn_mfma_f32_16x16x32_f16(af[mi], bf[ni], acc[mi][ni], 0, 0, 0);
    }
    const bool addb = bias && (!SPLITK || blockIdx.z == 0);
    #pragma unroll
    for (int mi = 0; mi < 2; ++mi)
        #pragma unroll
        for (int ni = 0; ni < 8; ++ni)
            #pragma unroll
            for (int i = 0; i < 4; ++i) {
                int row = row0 + w * 32 + mi * 16 + g * 4 + i;
                int col = col0 + ni * 16 + c;
                float v = acc[mi][ni][i] + (addb ? bias[col] : 0.f);
                if (ACT == 1) v = fmaxf(v, 0.f) + log1pf(expf(-fabsf(v)));
                else if (ACT == 2) v = v / (1.f + expf(-v));
                if (SPLITK)       atomicAdd((float*)Cv + (size_t)row * ldc + col, v);
                else if (OUT_F32) ((float*)Cv)[(size_t)row * ldc + col] = v;
                else              ((_Float16*)Cv)[(size_t)row * ldc + col] = (_Float16)v;
            }
}

// ---------------- fused edge kernel v5: 1 barrier/chunk, dbuf panels, reg prefetch ----
// Per block: 16 edges = 64 edge-head rows, 4 waves. Wave w owns St rows 16w..16w+15
// in ALL phases (P3-write, t-build, GEMM2-read) -> no block sync needed between them.
// Weight panels double-buffered; next chunk's panel loads + gather loads issued early.
#define EB2 16
#define RW2 64

__global__ __launch_bounds__(256, 3) void fused_edge_kernel(
    const _Float16* __restrict__ qkvs,   // [2048][1664]
    const _Float16* __restrict__ e16,    // [65536][128]
    const _Float16* __restrict__ p12,    // [8192][768]
    const _Float16* __restrict__ wm3T,   // [384][128]
    const _Float16* __restrict__ wmsgT,  // [128][384]
    const float* __restrict__ bm, const float* __restrict__ lag, const float* __restrict__ lab,
    const float* __restrict__ bmsg, const float* __restrict__ lmg, const float* __restrict__ lmb,
    const int* __restrict__ src, const int* __restrict__ dst,
    float* __restrict__ agg)
{
    __shared__ alignas(16) _Float16 St [RW2 * 40];       // p3 chunk -> t chunk; stats scratch
    __shared__ alignas(16) _Float16 Bs3[2][32 * 136];
    __shared__ alignas(16) _Float16 Bsg[2][128 * 40];
    __shared__ float2 murs[RW2];
    __shared__ int dstn[EB2], srcn[EB2];

    const int tid = threadIdx.x;
    const int w = tid >> 6, l = tid & 63;
    const int g = l >> 4, c = l & 15;
    const int e0 = blockIdx.x * EB2;
    const int row0 = blockIdx.x * RW2;
    const float ISQ = 0.05103103630798287f;  // 1/sqrt(384)

    if (tid < EB2) { dstn[tid] = dst[e0 + tid]; srcn[tid] = src[e0 + tid]; }

    // P3 A-fragments: e rows contiguous; reused for every chunk. (row = row0+w*16+c)
    f16x8 af3[4];
    {
        const _Float16* ep = e16 + (size_t)(row0 + w * 16 + c) * 128;
        #pragma unroll
        for (int ks = 0; ks < 4; ++ks) af3[ks] = *(const f16x8*)(ep + ks * 32 + g * 8);
    }
    __syncthreads();   // dstn/srcn visible

    // ---- phase 1: parallel alpha LN stats ----
    {
        int r = tid & 63, piece = tid >> 6;
        int el = r >> 2, hh = r & 3;
        int ni = dstn[el], nj = srcn[el];
        const _Float16* qp  = qkvs + (size_t)ni * 1664 + hh * 128 + piece * 32;
        const _Float16* kip = qkvs + (size_t)ni * 1664 + 512 + hh * 128 + piece * 32;
        const _Float16* kjp = qkvs + (size_t)nj * 1664 + 512 + hh * 128 + piece * 32;
        const _Float16* ep  = e16 + (size_t)(row0 + r) * 128 + piece * 32;
        float s1 = 0.f, s2 = 0.f;
        #pragma unroll
        for (int v = 0; v < 4; ++v) {
            f16x8 qv  = *(const f16x8*)(qp + v * 8);
            f16x8 kiv = *(const f16x8*)(kip + v * 8);
            f16x8 kjv = *(const f16x8*)(kjp + v * 8);
            f16x8 ev  = *(const f16x8*)(ep + v * 8);
            #pragma unroll
            for (int j = 0; j < 8; ++j) {
                float q = (float)qv[j];
                float a0 = q * (float)kiv[j] * ISQ;
                float a1 = q * (float)kjv[j] * ISQ;
                float a2 = q * (float)ev[j] * ISQ;
                s1 += a0 + a1 + a2;
                s2 += a0 * a0 + a1 * a1 + a2 * a2;
            }
        }
        ((float2*)St)[piece * 64 + r] = make_float2(s1, s2);
    }
    __syncthreads();
    if (tid < 64) {
        float2* red = (float2*)St;
        float S1 = 0.f, S2 = 0.f;
        #pragma unroll
        for (int p = 0; p < 4; ++p) { float2 v = red[p * 64 + tid]; S1 += v.x; S2 += v.y; }
        float mu = S1 * (1.f / 384.f);
        float var = S2 * (1.f / 384.f) - mu * mu;
        murs[tid] = make_float2(mu, rsqrtf(var + EPSV));
    }

    // per-thread t-build pointers (thread owns row r_own = tid>>2, cols cp*8 per chunk)
    const int r_own = tid >> 2, cp = tid & 3;
    const int edge_o = r_own >> 2, hh_o = r_own & 3;
    const int nd_o = dstn[edge_o], ns_o = srcn[edge_o];
    const _Float16* qpo  = qkvs + (size_t)nd_o * 1664 + hh_o * 128;
    const _Float16* kipo = qkvs + (size_t)nd_o * 1664 + 512 + hh_o * 128;
    const _Float16* kjpo = qkvs + (size_t)ns_o * 1664 + 512 + hh_o * 128;
    const _Float16* epo  = e16 + (size_t)(row0 + r_own) * 128;
    const _Float16* p1p  = p12 + ((size_t)nd_o * 4 + hh_o) * 768;
    const _Float16* p2p  = p12 + ((size_t)ns_o * 4 + hh_o) * 768 + 384;

    // stage-load index precompute (same thread->slot map for load and write)
    const int s3c0 = tid >> 4,        s3q0 = tid & 15;         // Bs3 slot, i=0
    const int s3c1 = (tid + 256) >> 4, s3q1 = tid & 15;        // i=1
    const int sgc0 = tid >> 2,        sgq0 = tid & 3;          // Bsg slot, i=0
    const int sgc1 = (tid + 256) >> 2, sgq1 = tid & 3;         // i=1

    // prologue: stage B[0] directly; prefetch gather loads for ck=0
    {
        *(f16x8*)&Bs3[0][s3c0 * 136 + s3q0 * 8] = *(const f16x8*)&wm3T[(size_t)s3c0 * 128 + s3q0 * 8];
        *(f16x8*)&Bs3[0][s3c1 * 136 + s3q1 * 8] = *(const f16x8*)&wm3T[(size_t)s3c1 * 128 + s3q1 * 8];
        *(f16x8*)&Bsg[0][sgc0 * 40 + sgq0 * 8] = *(const f16x8*)&wmsgT[(size_t)sgc0 * 384 + sgq0 * 8];
        *(f16x8*)&Bsg[0][sgc1 * 40 + sgq1 * 8] = *(const f16x8*)&wmsgT[(size_t)sgc1 * 384 + sgq1 * 8];
    }
    f16x8 qv_n, sv_n, p1v_n, p2v_n;
    {
        int kk0 = cp * 8;                       // ck = 0
        qv_n  = *(const f16x8*)(qpo + kk0);
        sv_n  = *(const f16x8*)(kipo + kk0);    // s=0 for ck<4
        p1v_n = *(const f16x8*)(p1p + kk0);
        p2v_n = *(const f16x8*)(p2p + kk0);
    }

    // ---- main loop: 12 chunks, ONE barrier per chunk ----
    f32x4 acc2[8] = {};
    #pragma unroll 1
    for (int ck = 0; ck < 12; ++ck) {
        __syncthreads();   // B[ck] staged (prev iter's ds_writes + prologue), murs visible

        const int b = ck & 1, bn = b ^ 1;
        const bool do_stage = (ck < 11);

        // rotate prefetched gathers
        f16x8 qv = qv_n, sv = sv_n, p1v = p1v_n, p2v = p2v_n;

        // issue next chunk's loads early (stage panels -> regs, gathers -> regs)
        f16x8 sb3_0, sb3_1, sbg_0, sbg_1;
        if (do_stage) {
            int ckn = ck + 1;
            sb3_0 = *(const f16x8*)&wm3T[(size_t)(ckn * 32 + s3c0) * 128 + s3q0 * 8];
            sb3_1 = *(const f16x8*)&wm3T[(size_t)(ckn * 32 + s3c1) * 128 + s3q1 * 8];
            sbg_0 = *(const f16x8*)&wmsgT[(size_t)sgc0 * 384 + ckn * 32 + sgq0 * 8];
            sbg_1 = *(const f16x8*)&wmsgT[(size_t)sgc1 * 384 + ckn * 32 + sgq1 * 8];
            int kk0 = ckn * 32 + cp * 8;
            int s = kk0 >> 7, cc0 = kk0 & 127;
            const _Float16* selp = (s == 0) ? kipo : (s == 1) ? kjpo : epo;
            qv_n  = *(const f16x8*)(qpo + cc0);
            sv_n  = *(const f16x8*)(selp + cc0);
            p1v_n = *(const f16x8*)(p1p + kk0);
            p2v_n = *(const f16x8*)(p2p + kk0);
        }

        // P3 chunk: wave w -> St rows w*16.., 32 cols (same-wave write)
        f32x4 a3[2] = {};
        #pragma unroll
        for (int ks = 0; ks < 4; ++ks)
            #pragma unroll
            for (int nt = 0; nt < 2; ++nt) {
                f16x8 bf = *(const f16x8*)&Bs3[b][(nt * 16 + c) * 136 + ks * 32 + g * 8];
                a3[nt] = __builtin_amdgcn_mfma_f32_16x16x32_f16(af3[ks], bf, a3[nt], 0, 0, 0);
            }
        #pragma unroll
        for (int nt = 0; nt < 2; ++nt)
            #pragma unroll
            for (int i = 0; i < 4; ++i)
                St[(w * 16 + g * 4 + i) * 40 + nt * 16 + c] = (_Float16)a3[nt][i];

        // t-build in place (same-wave St rw; gathers from prefetched regs)
        {
            int kk0 = ck * 32 + cp * 8;
            f16x8 p3v = *(const f16x8*)&St[r_own * 40 + cp * 8];
            F4 lg0 = *(const F4*)(lag + kk0), lg1 = *(const F4*)(lag + kk0 + 4);
            F4 lb0 = *(const F4*)(lab + kk0), lb1 = *(const F4*)(lab + kk0 + 4);
            F4 bm0 = *(const F4*)(bm + kk0),  bm1 = *(const F4*)(bm + kk0 + 4);
            float2 mr = murs[r_own];
            H8 tv;
            #pragma unroll
            for (int j = 0; j < 8; ++j) {
                float lgv = (j < 4) ? lg0.v[j] : lg1.v[j - 4];
                float lbv = (j < 4) ? lb0.v[j] : lb1.v[j - 4];
                float bmv = (j < 4) ? bm0.v[j] : bm1.v[j - 4];
                float a = (float)qv[j] * (float)sv[j] * ISQ;
                float z = (a - mr.x) * mr.y * lgv + lbv;
                float gate = 1.f / (1.f + __expf(-z));
                float t = (float)p1v[j] + (float)p2v[j] + (float)p3v[j] + bmv;
                tv.h[j] = (_Float16)(t * gate);
            }
            *(f16x8*)&St[r_own * 40 + cp * 8] = tv.h;
        }

        // GEMM2 accumulate: wave w -> St rows w*16.. (same-wave read), all 8 n-tiles
        {
            f16x8 af2 = *(const f16x8*)&St[(w * 16 + c) * 40 + g * 8];
            #pragma unroll
            for (int ni = 0; ni < 8; ++ni) {
                f16x8 bf = *(const f16x8*)&Bsg[b][(ni * 16 + c) * 40 + g * 8];
                acc2[ni] = __builtin_amdgcn_mfma_f32_16x16x32_f16(af2, bf, acc2[ni], 0, 0, 0);
            }
        }

        // write next chunk's panels into the other buffer (loads have had the
        // whole chunk body to land; safe: last readers of bn finished before
        // the barrier at the top of this iteration)
        if (do_stage) {
            *(f16x8*)&Bs3[bn][s3c0 * 136 + s3q0 * 8] = sb3_0;
            *(f16x8*)&Bs3[bn][s3c1 * 136 + s3q1 * 8] = sb3_1;
            *(f16x8*)&Bsg[bn][sgc0 * 40 + sgq0 * 8] = sbg_0;
            *(f16x8*)&Bsg[bn][sgc1 * 40 + sgq1 * 8] = sbg_1;
        }
    }

    // ---- epilogue: +bmsg, row-LN(128), scatter-add (rows w*16 + g*4 + i) ----
    float bz[8], lgv2[8], lbv2[8];
    #pragma unroll
    for (int ni = 0; ni < 8; ++ni) {
        int colc = ni * 16 + c;
        bz[ni] = bmsg[colc]; lgv2[ni] = lmg[colc]; lbv2[ni] = lmb[colc];
    }
    #pragma unroll
    for (int i = 0; i < 4; ++i) {
        float u[8];
        float s1 = 0.f, s2 = 0.f;
        #pragma unroll
        for (int ni = 0; ni < 8; ++ni) {
            u[ni] = acc2[ni][i] + bz[ni];
            s1 += u[ni]; s2 += u[ni] * u[ni];
        }
        #pragma unroll
        for (int off = 1; off < 16; off <<= 1) {
            s1 += __shfl_xor(s1, off);
            s2 += __shfl_xor(s2, off);
        }
        float mu = s1 * (1.f / 128.f);
        float var = s2 * (1.f / 128.f) - mu * mu;
        float rs = rsqrtf(var + EPSV);
        int r = w * 16 + g * 4 + i;
        int el = r >> 2, hh = r & 3;
        int nd = dstn[el];
        float* ap = agg + (size_t)nd * HC_ + hh * CC_;
        #pragma unroll
        for (int ni = 0; ni < 8; ++ni) {
            float msg = (u[ni] - mu) * rs * lgv2[ni] + lbv2[ni];
            atomicAdd(ap + ni * 16 + c, msg);
        }
    }
}

// ---------------- BN stats over nodes (per channel) ----------------
__global__ void bn_stats_kernel(const float* __restrict__ outb,
                                float* __restrict__ mu, float* __restrict__ rv)
{
    int c = blockIdx.x;
    int tid = threadIdx.x;
    float s = 0.f, s2 = 0.f;
    for (int r = tid; r < N_NODES; r += 256) {
        float x = outb[(size_t)r * CC_ + c];
        s += x; s2 += x * x;
    }
    #pragma unroll
    for (int off = 1; off < 64; off <<= 1) {
        s += __shfl_xor(s, off);
        s2 += __shfl_xor(s2, off);
    }
    __shared__ float ls[8];
    int w = tid >> 6, ln = tid & 63;
    if (ln == 0) { ls[w] = s; ls[4 + w] = s2; }
    __syncthreads();
    if (tid == 0) {
        float S = ls[0] + ls[1] + ls[2] + ls[3];
        float S2 = ls[4] + ls[5] + ls[6] + ls[7];
        float m = S * (1.f / N_NODES);
        float var = S2 * (1.f / N_NODES) - m * m;
        mu[c] = m;
        rv[c] = rsqrtf(var + EPSV);
    }
}

// ---------------- BN apply + silu + residual(skip) -> h16 ----------------
__global__ void bn_apply_kernel(const float* __restrict__ outb, const _Float16* __restrict__ qkvs,
                                const float* __restrict__ mu, const float* __restrict__ rv,
                                const float* __restrict__ g, const float* __restrict__ b,
                                _Float16* __restrict__ h16)
{
    int idx = blockIdx.x * 256 + threadIdx.x;
    int n = idx >> 7, c = idx & (CC_ - 1);
    float x = (outb[idx] - mu[c]) * rv[c] * g[c] + b[c];
    x = x / (1.f + expf(-x));
    float skip = (float)qkvs[(size_t)n * 1664 + 1536 + c];
    h16[idx] = (_Float16)(x + skip);
}

// ---------------- output head + batch correction ----------------
__global__ void head_kernel(const float* __restrict__ feat, const float* __restrict__ fcow,
                            const float* __restrict__ fcob, const int* __restrict__ batch,
                            float* __restrict__ out, float* __restrict__ qa_buf,
                            float* __restrict__ qsum, float* __restrict__ cnt)
{
    int n = blockIdx.x * 256 + threadIdx.x;
    float ea = fcob[0], qa = fcob[1];
    for (int j = 0; j < DD; ++j) {
        float f = feat[(size_t)n * DD + j];
        ea += f * fcow[2 * j];
        qa += f * fcow[2 * j + 1];
    }
    out[2 * n] = ea;
    qa_buf[n] = qa;
    int b = batch[n];
    atomicAdd(&qsum[b], qa);
    atomicAdd(&cnt[b], 1.0f);
}

__global__ void final_kernel(const float* __restrict__ qa_buf, const int* __restrict__ batch,
                             const float* __restrict__ qsum, const float* __restrict__ cnt,
                             float* __restrict__ out)
{
    int n = blockIdx.x * 256 + threadIdx.x;
    int b = batch[n];
    out[2 * n + 1] = qa_buf[n] - qsum[b] / cnt[b];
}

// ---------------- launcher ----------------
extern "C" void kernel_launch(void* const* d_in, const int* in_sizes, int n_in,
                              void* d_out, int out_size, void* d_ws, size_t ws_size,
                              hipStream_t stream)
{
    const float* x         = (const float*)d_in[0];
    const float* edge_attr = (const float*)d_in[1];
    const int*   edge_index= (const int*)d_in[2];
    const int*   batch     = (const int*)d_in[3];
    const float* rbf_b1 = (const float*)d_in[7];
    const float* rbf_b2 = (const float*)d_in[9];
    const float* bcat = (const float*)d_in[18];
    const float* bm = (const float*)d_in[20];
    const float* lag = (const float*)d_in[21];
    const float* lab = (const float*)d_in[22];
    const float* bmsg = (const float*)d_in[24];
    const float* lmg = (const float*)d_in[25];
    const float* lmb = (const float*)d_in[26];
    const float* bn_g = (const float*)d_in[27];
    const float* bn_b = (const float*)d_in[28];
    const float* fc_b = (const float*)d_in[32];
    const float* fco_w = (const float*)d_in[33];
    const float* fco_b = (const float*)d_in[34];

    const int* src = edge_index;
    const int* dst = edge_index + NE;

    char* base = (char*)d_ws;
    size_t off = 0;
    auto alloc = [&](size_t bytes) -> char* {
        char* p = base + off;
        off += (bytes + 255) & ~(size_t)255;
        return p;
    };
    _Float16* wbuf   = (_Float16*)alloc((size_t)TOT_H * 2);
    float*    biasb  = (float*)alloc((size_t)5 * 1664 * 4);
    _Float16* x16    = (_Float16*)alloc((size_t)N_NODES * 96 * 2);
    _Float16* h16    = (_Float16*)alloc((size_t)N_NODES * DD * 2);
    _Float16* rbf16  = (_Float16*)alloc((size_t)NE * DD * 2);
    _Float16* tmp16  = (_Float16*)alloc((size_t)NE * DD * 2);
    _Float16* ef16   = (_Float16*)alloc((size_t)NE * DD * 2);
    _Float16* qkvs16 = (_Float16*)alloc((size_t)N_NODES * 1664 * 2);
    _Float16* ebuf16 = (_Float16*)alloc((size_t)NE * HC_ * 2);
    _Float16* p12    = (_Float16*)alloc((size_t)8192 * 768 * 2);
    float* agg    = (float*)alloc((size_t)N_NODES * HC_ * 4);
    float* outb   = (float*)alloc((size_t)N_NODES * CC_ * 4);   // contiguous after agg
    float* featb  = (float*)alloc((size_t)N_NODES * DD * 4);
    float* qa_buf = (float*)alloc((size_t)N_NODES * 4);
    float* mu     = (float*)alloc(CC_ * 4);
    float* rv     = (float*)alloc(CC_ * 4);
    float* qsum   = (float*)alloc((size_t)NB * 2 * 4);
    float* cnt    = qsum + NB;

    // ---- weight prep (all layers) + input packs ----
    wprep_kernel<<<(TOT_ALL + 255) / 256, 256, 0, stream>>>(
        (const float*)d_in[10], (const float*)d_in[11], (const float*)d_in[12], (const float*)d_in[13],
        (const float*)d_in[14], (const float*)d_in[15], (const float*)d_in[29], (const float*)d_in[30],
        (const float*)d_in[19], (const float*)d_in[23], (const float*)d_in[16], (const float*)d_in[17],
        (const float*)d_in[4], (const float*)d_in[6], (const float*)d_in[8], (const float*)d_in[31],
        wbuf, biasb);
    xpack_kernel<<<(N_NODES * 96 + 255) / 256, 256, 0, stream>>>(x, x16);
    rbf_kernel<<<(NE * 128) / 256, 256, 0, stream>>>(edge_attr, rbf16);

    // h = x @ emb + emb_b  (K=96 zero-padded)
    gemm16<0, 0, false, false><<<dim3(16, 1), 256, 0, stream>>>(
        x16, 96, wbuf + OFF_EMBT, 96, 0, (const float*)d_in[5], h16, DD, 96);
    // ef = softplus(rbf@w1+b1) @ w2 + b2
    gemm16<0, 1, false, false><<<dim3(NE / 128, 1), 256, 0, stream>>>(
        rbf16, 128, wbuf + OFF_W1T, 128, 0, rbf_b1, tmp16, 128, 128);
    gemm16<0, 0, false, false><<<dim3(NE / 128, 1), 256, 0, stream>>>(
        tmp16, 128, wbuf + OFF_W2T, 128, 0, rbf_b2, ef16, 128, 128);

    for (int l = 0; l < NL; ++l) {
        const _Float16* lw = wbuf + (size_t)l * LWH;
        const float* bias_l = biasb + (size_t)l * 1664;
        const float* bcat_l = bcat + (size_t)l * CC_;
        const float* bm_l = bm + (size_t)l * C3_;
        const float* lag_l = lag + (size_t)l * C3_;
        const float* lab_l = lab + (size_t)l * C3_;
        const float* bmsg_l = bmsg + (size_t)l * CC_;
        const float* lmg_l = lmg + (size_t)l * CC_;
        const float* lmb_l = lmb + (size_t)l * CC_;
        const float* bng_l = bn_g + (size_t)l * CC_;
        const float* bnb_l = bn_b + (size_t)l * CC_;

        // qkvs = h @ [wq|wk|wv|wskip] + [bq|bk|bv|bskip]
        gemm16<0, 0, false, false><<<dim3(16, 13), 256, 0, stream>>>(
            h16, DD, lw + OFF_QKVST, 128, 0, bias_l, qkvs16, 1664, 128);
        // e = ef @ we
        gemm16<0, 0, false, false><<<dim3(NE / 128, 4), 256, 0, stream>>>(
            ef16, 128, lw + OFF_WET, 128, 0, nullptr, ebuf16, HC_, 128);
        // P1|P2 = v @ [wm_top | wm_mid]
        gemm16<2, 0, false, false><<<dim3(64, 6), 256, 0, stream>>>(
            qkvs16 + 1024, 1664, lw + OFF_W12T, 128, 0, nullptr, p12, 768, 128);

        // fused: P3 + gate + GEMM2 + row-LN + segment scatter
        hipMemsetAsync(agg, 0, ((size_t)N_NODES * HC_ + (size_t)N_NODES * CC_) * sizeof(float), stream);
        fused_edge_kernel<<<NE / EB2, 256, 0, stream>>>(
            qkvs16, ebuf16, p12, lw + OFF_WM3T, lw + OFF_WMSGT,
            bm_l, lag_l, lab_l, bmsg_l, lmg_l, lmb_l, src, dst, agg);

        // outb = agg @ wcat + bcat (split-K), BN, silu, +skip -> h16
        gemm16<1, 0, false, true><<<dim3(16, 1, 4), 256, 0, stream>>>(
            agg, HC_, lw + OFF_WCATT, 512, 0, bcat_l, outb, CC_, 512);
        bn_stats_kernel<<<CC_, 256, 0, stream>>>(outb, mu, rv);
        bn_apply_kernel<<<(N_NODES * CC_) / 256, 256, 0, stream>>>(
            outb, qkvs16, mu, rv, bng_l, bnb_l, h16);
    }

    // feat = silu(h @ fc_w + fc_b)
    gemm16<0, 2, true, false><<<dim3(16, 1), 256, 0, stream>>>(
        h16, DD, wbuf + OFF_FCT, 128, 0, fc_b, featb, DD, 128);

    hipMemsetAsync(qsum, 0, (size_t)NB * 2 * sizeof(float), stream);
    head_kernel<<<N_NODES / 256, 256, 0, stream>>>(featb, fco_w, fco_b, batch,
                                                   (float*)d_out, qa_buf, qsum, cnt);
    final_kernel<<<N_NODES / 256, 256, 0, stream>>>(qa_buf, batch, qsum, cnt, (float*)d_out);
}